// Round 1
// baseline (2060.832 us; speedup 1.0000x reference)
//
#include <hip/hip_runtime.h>

typedef unsigned short u16;
typedef __bf16 bf16x8 __attribute__((ext_vector_type(8)));
typedef float f32x4 __attribute__((ext_vector_type(4)));

// fp32 -> bf16 round-to-nearest-even (bit trick; NaN not expected here)
__device__ __forceinline__ u16 f2bf(float f) {
    union { float f; unsigned int u; } c; c.f = f;
    unsigned int u = c.u;
    unsigned int r = (u + 0x7FFFu + ((u >> 16) & 1u)) >> 16;
    return (u16)r;
}

__device__ __forceinline__ float gelu_f(float v) {
    const float c = 0.7978845608028654f;
    float t = tanhf(c * (v + 0.044715f * v * v * v));
    return 0.5f * v * (1.0f + t);
}

// ---------------------------------------------------------------- embedding
// x[t,d] = wte[idx[t], d]   (fp32, residual stream)
// y[t,d] = bf16( d even: sin(age/365.25 * div[d/2]); odd: cos(...) )
__global__ __launch_bounds__(256) void embed_kernel(
    const int* __restrict__ idx, const float* __restrict__ age,
    const float* __restrict__ wte, float* __restrict__ x, u16* __restrict__ y)
{
    int t = blockIdx.x;
    int tid = threadIdx.x;
    int tok = idx[t];
    float a = age[t] * (1.0f / 365.25f);
    const float kc = -9.210340371976184f / 768.0f;   // -ln(10000)/D
#pragma unroll
    for (int j = 0; j < 3; j++) {
        int d = tid + j * 256;
        x[(size_t)t * 768 + d] = wte[(size_t)tok * 768 + d];
        int twoi = d & ~1;
        float dv = __expf(kc * (float)twoi);
        float ang = a * dv;
        float val = (d & 1) ? __cosf(ang) : __sinf(ang);
        y[(size_t)t * 768 + d] = f2bf(val);
    }
}

// ---------------------------------------------------------------- layernorm
__global__ __launch_bounds__(256) void ln_kernel(
    const float* __restrict__ x, const float* __restrict__ w,
    const float* __restrict__ b, u16* __restrict__ out)
{
    int row = blockIdx.x;
    int tid = threadIdx.x;
    int l = tid & 63, wv = tid >> 6;
    const float* xr = x + (size_t)row * 768;
    float v[3], s = 0.f, ss = 0.f;
#pragma unroll
    for (int j = 0; j < 3; j++) { v[j] = xr[tid + j * 256]; s += v[j]; ss += v[j] * v[j]; }
#pragma unroll
    for (int d = 1; d < 64; d <<= 1) { s += __shfl_xor(s, d); ss += __shfl_xor(ss, d); }
    __shared__ float ps[4], pss[4];
    if (l == 0) { ps[wv] = s; pss[wv] = ss; }
    __syncthreads();
    s = ps[0] + ps[1] + ps[2] + ps[3];
    ss = pss[0] + pss[1] + pss[2] + pss[3];
    float mu = s * (1.0f / 768.0f);
    float var = ss * (1.0f / 768.0f) - mu * mu;
    float rstd = rsqrtf(var + 1e-5f);
#pragma unroll
    for (int j = 0; j < 3; j++) {
        int d = tid + j * 256;
        out[(size_t)row * 768 + d] = f2bf((v[j] - mu) * rstd * w[d] + b[d]);
    }
}

// ---------------------------------------------------------------- GEMM
// C[M,N] = A[M,K](bf16) @ W[N,K]^T(fp32, converted to bf16 in staging) + bias
// EPI: 0 = bf16 out, 1 = bf16 gelu out, 2 = f32 out += resid, 3 = f32 out
enum { EPI_BF16 = 0, EPI_BF16_GELU = 1, EPI_F32_RESID = 2, EPI_F32 = 3 };

template <int EPI>
__global__ __launch_bounds__(256) void gemm_kernel(
    const u16* __restrict__ A, const float* __restrict__ Bw,
    const float* __restrict__ bias, const float* resid, void* out,
    int N, int K)
{
    constexpr int M = 2048;
    __shared__ u16 As[128][40];   // 80B rows (16B pad) to break bank conflicts
    __shared__ u16 Bs[128][40];
    int tid = threadIdx.x;
    int l = tid & 63, w = tid >> 6;
    int lw = l & 15, lg = l >> 4;
    int mtiles = M / 128;
    int mt = blockIdx.x % mtiles, nt = blockIdx.x / mtiles;
    int row0 = mt * 128, col0 = nt * 128;
    int mbase = (w & 1) * 64, nbase = (w >> 1) * 64;
    f32x4 acc[4][4] = {};

    for (int kk = 0; kk < K; kk += 32) {
        // stage A: 128x32 bf16, 512 16B-chunks
        int c = tid;
#pragma unroll
        for (int i = 0; i < 2; i++, c += 256) {
            int r = c >> 2, q = c & 3;
            uint4 u = *reinterpret_cast<const uint4*>(A + (size_t)(row0 + r) * K + kk + q * 8);
            *reinterpret_cast<uint4*>(&As[r][q * 8]) = u;
        }
        // stage B: 128x32 fp32 -> bf16, 1024 float4-chunks
        int c2 = tid;
#pragma unroll
        for (int i = 0; i < 4; i++, c2 += 256) {
            int r = c2 >> 3, q = c2 & 7;
            const float4 f = *reinterpret_cast<const float4*>(Bw + (size_t)(col0 + r) * K + kk + q * 4);
            union { u16 h[4]; uint2 u; } cv;
            cv.h[0] = f2bf(f.x); cv.h[1] = f2bf(f.y); cv.h[2] = f2bf(f.z); cv.h[3] = f2bf(f.w);
            *reinterpret_cast<uint2*>(&Bs[r][q * 4]) = cv.u;
        }
        __syncthreads();
        bf16x8 af[4], bfr[4];
#pragma unroll
        for (int mi = 0; mi < 4; mi++)
            af[mi] = *reinterpret_cast<const bf16x8*>(&As[mbase + mi * 16 + lw][lg * 8]);
#pragma unroll
        for (int ni = 0; ni < 4; ni++)
            bfr[ni] = *reinterpret_cast<const bf16x8*>(&Bs[nbase + ni * 16 + lw][lg * 8]);
#pragma unroll
        for (int mi = 0; mi < 4; mi++)
#pragma unroll
            for (int ni = 0; ni < 4; ni++)
                acc[mi][ni] = __builtin_amdgcn_mfma_f32_16x16x32_bf16(af[mi], bfr[ni], acc[mi][ni], 0, 0, 0);
        __syncthreads();
    }

#pragma unroll
    for (int mi = 0; mi < 4; mi++) {
#pragma unroll
        for (int ni = 0; ni < 4; ni++) {
            int colc = col0 + nbase + ni * 16 + lw;
            float bv = bias ? bias[colc] : 0.0f;
#pragma unroll
            for (int j = 0; j < 4; j++) {
                int row = row0 + mbase + mi * 16 + lg * 4 + j;
                size_t off = (size_t)row * N + colc;
                float v = acc[mi][ni][j] + bv;
                if constexpr (EPI == EPI_BF16) {
                    ((u16*)out)[off] = f2bf(v);
                } else if constexpr (EPI == EPI_BF16_GELU) {
                    ((u16*)out)[off] = f2bf(gelu_f(v));
                } else if constexpr (EPI == EPI_F32_RESID) {
                    ((float*)out)[off] = v + resid[off];
                } else {
                    ((float*)out)[off] = v;
                }
            }
        }
    }
}

// ---------------------------------------------------------------- attention
// one block = (b, h, 64 q-rows); 4 waves x 16 q-rows; kv tiles of 32; online softmax
__global__ __launch_bounds__(256) void attn_kernel(
    const u16* __restrict__ qkv, const int* __restrict__ idx, u16* __restrict__ yv)
{
    __shared__ u16 Kt[32][72];      // K-tile [kv][hd], padded rows (144B)
    __shared__ u16 Vt[64][40];      // V-tile transposed [hd][kv], padded rows (80B)
    __shared__ u16 Pb[4][16][40];   // per-wave P transpose buffer
    __shared__ int kval[32];

    int tid = threadIdx.x, l = tid & 63, w = tid >> 6;
    int lw = l & 15, lg = l >> 4;
    int bid = blockIdx.x;
    int qb = bid & 15;
    int h = (bid >> 4) % 12;
    int b = bid / (16 * 12);
    const size_t base = (size_t)b * 1024;

    // Q fragments (A-operand): rows qb*64 + w*16 + lw, k-halves 0-31 / 32-63
    int qrow = qb * 64 + w * 16 + lw;
    const u16* qp = qkv + (base + qrow) * 2304 + h * 64;
    bf16x8 aq0 = *reinterpret_cast<const bf16x8*>(qp + lg * 8);
    bf16x8 aq1 = *reinterpret_cast<const bf16x8*>(qp + 32 + lg * 8);

    int rowj[4], vq[4];
#pragma unroll
    for (int j = 0; j < 4; j++) {
        rowj[j] = qb * 64 + w * 16 + lg * 4 + j;
        vq[j] = idx[base + rowj[j]] > 0;
    }
    float m[4], lsum[4];
    f32x4 O[4] = {};
#pragma unroll
    for (int j = 0; j < 4; j++) { m[j] = -__builtin_inff(); lsum[j] = 0.0f; }

    int kvend = qb * 64 + 64;
    for (int kv0 = 0; kv0 < kvend; kv0 += 32) {
        { // cooperative staging
            int r = tid >> 3, cc = tid & 7;
            const u16* kp = qkv + (base + kv0 + r) * 2304 + 768 + h * 64 + cc * 8;
            uint4 ku = *reinterpret_cast<const uint4*>(kp);
            *reinterpret_cast<uint4*>(&Kt[r][cc * 8]) = ku;
            const u16* vp = qkv + (base + kv0 + r) * 2304 + 1536 + h * 64 + cc * 8;
            union { uint4 u; u16 h8[8]; } vu;
            vu.u = *reinterpret_cast<const uint4*>(vp);
#pragma unroll
            for (int j2 = 0; j2 < 8; j2++) Vt[cc * 8 + j2][r] = vu.h8[j2];
            if (tid < 32) kval[tid] = idx[base + kv0 + tid] > 0;
        }
        __syncthreads();

        // S = Q K^T  (two 16-col groups)
        f32x4 S[2];
#pragma unroll
        for (int g = 0; g < 2; g++) {
            bf16x8 bk0 = *reinterpret_cast<const bf16x8*>(&Kt[g * 16 + lw][lg * 8]);
            bf16x8 bk1 = *reinterpret_cast<const bf16x8*>(&Kt[g * 16 + lw][32 + lg * 8]);
            f32x4 t = {};
            t = __builtin_amdgcn_mfma_f32_16x16x32_bf16(aq0, bk0, t, 0, 0, 0);
            t = __builtin_amdgcn_mfma_f32_16x16x32_bf16(aq1, bk1, t, 0, 0, 0);
            S[g] = t;
        }
        float p[2][4];
#pragma unroll
        for (int j = 0; j < 4; j++) {
            float sv0, sv1;
#pragma unroll
            for (int g = 0; g < 2; g++) {
                int kcol = kv0 + g * 16 + lw;
                float s = S[g][j] * 0.125f;
                bool keep = (kcol <= rowj[j]) &&
                            ((vq[j] && kval[g * 16 + lw]) || (kcol == rowj[j]));
                s = keep ? s : -__builtin_inff();
                if (g) sv1 = s; else sv0 = s;
            }
            float mx = fmaxf(sv0, sv1);
            mx = fmaxf(mx, __shfl_xor(mx, 1));
            mx = fmaxf(mx, __shfl_xor(mx, 2));
            mx = fmaxf(mx, __shfl_xor(mx, 4));
            mx = fmaxf(mx, __shfl_xor(mx, 8));
            float mn = fmaxf(m[j], mx);
            float mclamp = fmaxf(mn, -1e30f);          // avoid inf-inf NaN
            float scale = __expf(m[j] - mclamp);       // m=-inf -> 0 (l,O are 0 then)
            float p0 = __expf(sv0 - mclamp);
            float p1 = __expf(sv1 - mclamp);
            float rs = p0 + p1;
            rs += __shfl_xor(rs, 1); rs += __shfl_xor(rs, 2);
            rs += __shfl_xor(rs, 4); rs += __shfl_xor(rs, 8);
            lsum[j] = lsum[j] * scale + rs;
            m[j] = mn;
#pragma unroll
            for (int ni = 0; ni < 4; ni++) O[ni][j] *= scale;
            p[0][j] = p0; p[1][j] = p1;
        }
        // transpose P (C-layout) -> A-frag layout through per-wave LDS
#pragma unroll
        for (int g = 0; g < 2; g++)
#pragma unroll
            for (int j = 0; j < 4; j++)
                Pb[w][lg * 4 + j][g * 16 + lw] = f2bf(p[g][j]);
        bf16x8 ap = *reinterpret_cast<const bf16x8*>(&Pb[w][lw][lg * 8]);
#pragma unroll
        for (int ni = 0; ni < 4; ni++) {
            bf16x8 bv = *reinterpret_cast<const bf16x8*>(&Vt[ni * 16 + lw][lg * 8]);
            O[ni] = __builtin_amdgcn_mfma_f32_16x16x32_bf16(ap, bv, O[ni], 0, 0, 0);
        }
        __syncthreads();
    }

#pragma unroll
    for (int j = 0; j < 4; j++) {
        float inv = 1.0f / lsum[j];
#pragma unroll
        for (int ni = 0; ni < 4; ni++) {
            float v = O[ni][j] * inv;
            yv[(base + rowj[j]) * 768 + h * 64 + ni * 16 + lw] = f2bf(v);
        }
    }
}

// ---------------------------------------------------------------- host
static void launch_gemm(int epi, const u16* A, const float* Bw, const float* bias,
                        const float* resid, void* out, int N, int K, hipStream_t s)
{
    dim3 grid((2048 / 128) * (N / 128));
    dim3 blk(256);
    switch (epi) {
        case EPI_BF16:      gemm_kernel<EPI_BF16><<<grid, blk, 0, s>>>(A, Bw, bias, resid, out, N, K); break;
        case EPI_BF16_GELU: gemm_kernel<EPI_BF16_GELU><<<grid, blk, 0, s>>>(A, Bw, bias, resid, out, N, K); break;
        case EPI_F32_RESID: gemm_kernel<EPI_F32_RESID><<<grid, blk, 0, s>>>(A, Bw, bias, resid, out, N, K); break;
        default:            gemm_kernel<EPI_F32><<<grid, blk, 0, s>>>(A, Bw, bias, resid, out, N, K); break;
    }
}

extern "C" void kernel_launch(void* const* d_in, const int* in_sizes, int n_in,
                              void* d_out, int out_size, void* d_ws, size_t ws_size,
                              hipStream_t stream)
{
    (void)in_sizes; (void)n_in; (void)out_size; (void)ws_size;
    const int*   idx    = (const int*)  d_in[0];
    const float* age    = (const float*)d_in[1];
    const float* wte    = (const float*)d_in[2];
    const float* wae_w  = (const float*)d_in[3];
    const float* ln1_w  = (const float*)d_in[4];
    const float* ln1_b  = (const float*)d_in[5];
    const float* attn_w = (const float*)d_in[6];
    const float* attn_b = (const float*)d_in[7];
    const float* proj_w = (const float*)d_in[8];
    const float* proj_b = (const float*)d_in[9];
    const float* ln2_w  = (const float*)d_in[10];
    const float* ln2_b  = (const float*)d_in[11];
    const float* fc_w   = (const float*)d_in[12];
    const float* fc_b   = (const float*)d_in[13];
    const float* fc2_w  = (const float*)d_in[14];
    const float* fc2_b  = (const float*)d_in[15];
    const float* lnf_w  = (const float*)d_in[16];
    const float* lnf_b  = (const float*)d_in[17];

    char* ws = (char*)d_ws;
    size_t off = 0;
    float* x   = (float*)(ws + off); off += (size_t)2048 * 768 * 4;   // residual stream
    u16* hb    = (u16*)(ws + off);   off += (size_t)2048 * 768 * 2;   // LN output (bf16)
    u16* qkvb  = (u16*)(ws + off);   off += (size_t)2048 * 2304 * 2;  // qkv (bf16)
    u16* yvb   = (u16*)(ws + off);   off += (size_t)2048 * 768 * 2;   // attn out (bf16)
    u16* a1b   = (u16*)(ws + off);   off += (size_t)2048 * 3072 * 2;  // gelu(fc) (bf16)
    u16* yage  = (u16*)(ws + off);   off += (size_t)2048 * 768 * 2;   // age encoding (bf16)

    embed_kernel<<<2048, 256, 0, stream>>>(idx, age, wte, x, yage);
    launch_gemm(EPI_F32_RESID, yage, wae_w, nullptr, x, x, 768, 768, stream);

    for (int li = 0; li < 4; li++) {
        ln_kernel<<<2048, 256, 0, stream>>>(x, ln1_w + li * 768, ln1_b + li * 768, hb);
        launch_gemm(EPI_BF16, hb, attn_w + (size_t)li * 2304 * 768, attn_b + li * 2304,
                    nullptr, qkvb, 2304, 768, stream);
        attn_kernel<<<2 * 12 * 16, 256, 0, stream>>>(qkvb, idx, yvb);
        launch_gemm(EPI_F32_RESID, yvb, proj_w + (size_t)li * 768 * 768, proj_b + li * 768,
                    x, x, 768, 768, stream);
        ln_kernel<<<2048, 256, 0, stream>>>(x, ln2_w + li * 768, ln2_b + li * 768, hb);
        launch_gemm(EPI_BF16_GELU, hb, fc_w + (size_t)li * 3072 * 768, fc_b + li * 3072,
                    nullptr, a1b, 3072, 768, stream);
        launch_gemm(EPI_F32_RESID, a1b, fc2_w + (size_t)li * 768 * 3072, fc2_b + li * 768,
                    x, x, 768, 3072, stream);
    }

    ln_kernel<<<2048, 256, 0, stream>>>(x, lnf_w, lnf_b, hb);
    launch_gemm(EPI_F32, hb, wte, nullptr, nullptr, d_out, 32768, 768, stream);
}

// Round 3
// 1758.113 us; speedup vs baseline: 1.1722x; 1.1722x over previous
//
#include <hip/hip_runtime.h>

typedef unsigned short u16;
typedef __bf16 bf16x8 __attribute__((ext_vector_type(8)));
typedef float f32x4 __attribute__((ext_vector_type(4)));

// fp32 -> bf16 round-to-nearest-even
__device__ __forceinline__ u16 f2bf(float f) {
    union { float f; unsigned int u; } c; c.f = f;
    unsigned int u = c.u;
    unsigned int r = (u + 0x7FFFu + ((u >> 16) & 1u)) >> 16;
    return (u16)r;
}

__device__ __forceinline__ float gelu_f(float v) {
    const float c = 0.7978845608028654f;
    float t = tanhf(c * (v + 0.044715f * v * v * v));
    return 0.5f * v * (1.0f + t);
}

typedef const __attribute__((address_space(1))) unsigned int* as1_u32p;
typedef __attribute__((address_space(3))) unsigned int* as3_u32p;
__device__ __forceinline__ void gload16(const void* g, void* l) {
    __builtin_amdgcn_global_load_lds((as1_u32p)g, (as3_u32p)l, 16, 0, 0);
}

// ---------------------------------------------------------------- weight convert
__global__ __launch_bounds__(256) void cvt_kernel(
    const float* __restrict__ src, u16* __restrict__ dst, int n4)
{
    int i = blockIdx.x * 256 + threadIdx.x;
    int stride = gridDim.x * 256;
    for (; i < n4; i += stride) {
        float4 f = reinterpret_cast<const float4*>(src)[i];
        union { u16 h[4]; uint2 u; } cv;
        cv.h[0] = f2bf(f.x); cv.h[1] = f2bf(f.y);
        cv.h[2] = f2bf(f.z); cv.h[3] = f2bf(f.w);
        reinterpret_cast<uint2*>(dst)[i] = cv.u;
    }
}

// ---------------------------------------------------------------- embedding
__global__ __launch_bounds__(256) void embed_kernel(
    const int* __restrict__ idx, const float* __restrict__ age,
    const float* __restrict__ wte, float* __restrict__ x, u16* __restrict__ y)
{
    int t = blockIdx.x;
    int tid = threadIdx.x;
    int tok = idx[t];
    float a = age[t] * (1.0f / 365.25f);
    const float kc = -9.210340371976184f / 768.0f;   // -ln(10000)/D
#pragma unroll
    for (int j = 0; j < 3; j++) {
        int d = tid + j * 256;
        x[(size_t)t * 768 + d] = wte[(size_t)tok * 768 + d];
        int twoi = d & ~1;
        float dv = __expf(kc * (float)twoi);
        float ang = a * dv;
        float val = (d & 1) ? __cosf(ang) : __sinf(ang);
        y[(size_t)t * 768 + d] = f2bf(val);
    }
}

// ---------------------------------------------------------------- layernorm
__global__ __launch_bounds__(256) void ln_kernel(
    const float* __restrict__ x, const float* __restrict__ w,
    const float* __restrict__ b, u16* __restrict__ out)
{
    int row = blockIdx.x;
    int tid = threadIdx.x;
    int l = tid & 63, wv = tid >> 6;
    const float* xr = x + (size_t)row * 768;
    float v[3], s = 0.f, ss = 0.f;
#pragma unroll
    for (int j = 0; j < 3; j++) { v[j] = xr[tid + j * 256]; s += v[j]; ss += v[j] * v[j]; }
#pragma unroll
    for (int d = 1; d < 64; d <<= 1) { s += __shfl_xor(s, d); ss += __shfl_xor(ss, d); }
    __shared__ float ps[4], pss[4];
    if (l == 0) { ps[wv] = s; pss[wv] = ss; }
    __syncthreads();
    s = ps[0] + ps[1] + ps[2] + ps[3];
    ss = pss[0] + pss[1] + pss[2] + pss[3];
    float mu = s * (1.0f / 768.0f);
    float var = ss * (1.0f / 768.0f) - mu * mu;
    float rstd = rsqrtf(var + 1e-5f);
#pragma unroll
    for (int j = 0; j < 3; j++) {
        int d = tid + j * 256;
        out[(size_t)row * 768 + d] = f2bf((v[j] - mu) * rstd * w[d] + b[d]);
    }
}

// ---------------------------------------------------------------- GEMM (bf16 weights, global_load_lds, m97 structure)
// C[M=2048,N] = A[M,K](bf16) @ B[N,K](bf16)^T + bias ; XCD-swizzled grid, mt fastest
enum { EPI_BF16 = 0, EPI_BF16_GELU = 1, EPI_F32_RESID = 2, EPI_F32 = 3 };

template <int EPI>
__global__ __launch_bounds__(256) void gemm_lds_kernel(
    const u16* __restrict__ A, const u16* __restrict__ B,
    const float* __restrict__ bias, const float* resid, void* out,
    int N, int K, int mtiles, int nwg8)
{
    __shared__ u16 As[128][32];
    __shared__ u16 Bs[128][32];
    int tid = threadIdx.x;
    int l = tid & 63, w = tid >> 6;
    int lw = l & 15, lg = l >> 4;
    int bid = blockIdx.x;
    int wg = (bid & 7) * nwg8 + (bid >> 3);   // bijective XCD swizzle (nwg%8==0)
    int mt = wg % mtiles, nt = wg / mtiles;
    int row0 = mt * 128, col0 = nt * 128;
    int mbase = (w & 1) * 64, nbase = (w >> 1) * 64;

    // staging: wave w stages rows [w*32, w*32+32) of both 128x32 tiles
    int srow = w * 32 + (l >> 2);
    int scol = (l & 3) * 8;
    const u16* ga = A + (size_t)(row0 + srow) * K + scol;
    const u16* gb = B + (size_t)(col0 + srow) * K + scol;
    u16* lA0 = &As[w * 32][0];
    u16* lA1 = &As[w * 32 + 16][0];
    u16* lB0 = &Bs[w * 32][0];
    u16* lB1 = &Bs[w * 32 + 16][0];
    const size_t k16 = (size_t)16 * K;

    f32x4 acc[4][4] = {};
    for (int kk = 0; kk < K; kk += 32) {
        gload16(ga + kk, lA0);
        gload16(ga + k16 + kk, lA1);
        gload16(gb + kk, lB0);
        gload16(gb + k16 + kk, lB1);
        __syncthreads();
        bf16x8 af[4], bfr[4];
#pragma unroll
        for (int mi = 0; mi < 4; mi++)
            af[mi] = *reinterpret_cast<const bf16x8*>(&As[mbase + mi * 16 + lw][lg * 8]);
#pragma unroll
        for (int ni = 0; ni < 4; ni++)
            bfr[ni] = *reinterpret_cast<const bf16x8*>(&Bs[nbase + ni * 16 + lw][lg * 8]);
#pragma unroll
        for (int mi = 0; mi < 4; mi++)
#pragma unroll
            for (int ni = 0; ni < 4; ni++)
                acc[mi][ni] = __builtin_amdgcn_mfma_f32_16x16x32_bf16(af[mi], bfr[ni], acc[mi][ni], 0, 0, 0);
        __syncthreads();
    }

#pragma unroll
    for (int mi = 0; mi < 4; mi++) {
#pragma unroll
        for (int ni = 0; ni < 4; ni++) {
            int colc = col0 + nbase + ni * 16 + lw;
            float bv = bias ? bias[colc] : 0.0f;
#pragma unroll
            for (int j = 0; j < 4; j++) {
                int row = row0 + mbase + mi * 16 + lg * 4 + j;
                size_t off = (size_t)row * N + colc;
                float v = acc[mi][ni][j] + bv;
                if constexpr (EPI == EPI_BF16) {
                    ((u16*)out)[off] = f2bf(v);
                } else if constexpr (EPI == EPI_BF16_GELU) {
                    ((u16*)out)[off] = f2bf(gelu_f(v));
                } else if constexpr (EPI == EPI_F32_RESID) {
                    ((float*)out)[off] = v + resid[off];
                } else {
                    ((float*)out)[off] = v;
                }
            }
        }
    }
}

// ---------------------------------------------------------------- GEMM fallback (fp32 weights, round-1)
template <int EPI>
__global__ __launch_bounds__(256) void gemm_kernel(
    const u16* __restrict__ A, const float* __restrict__ Bw,
    const float* __restrict__ bias, const float* resid, void* out,
    int N, int K)
{
    constexpr int M = 2048;
    __shared__ u16 As[128][40];
    __shared__ u16 Bs[128][40];
    int tid = threadIdx.x;
    int l = tid & 63, w = tid >> 6;
    int lw = l & 15, lg = l >> 4;
    int mtiles = M / 128;
    int mt = blockIdx.x % mtiles, nt = blockIdx.x / mtiles;
    int row0 = mt * 128, col0 = nt * 128;
    int mbase = (w & 1) * 64, nbase = (w >> 1) * 64;
    f32x4 acc[4][4] = {};

    for (int kk = 0; kk < K; kk += 32) {
        int c = tid;
#pragma unroll
        for (int i = 0; i < 2; i++, c += 256) {
            int r = c >> 2, q = c & 3;
            uint4 u = *reinterpret_cast<const uint4*>(A + (size_t)(row0 + r) * K + kk + q * 8);
            *reinterpret_cast<uint4*>(&As[r][q * 8]) = u;
        }
        int c2 = tid;
#pragma unroll
        for (int i = 0; i < 4; i++, c2 += 256) {
            int r = c2 >> 3, q = c2 & 7;
            const float4 f = *reinterpret_cast<const float4*>(Bw + (size_t)(col0 + r) * K + kk + q * 4);
            union { u16 h[4]; uint2 u; } cv;
            cv.h[0] = f2bf(f.x); cv.h[1] = f2bf(f.y); cv.h[2] = f2bf(f.z); cv.h[3] = f2bf(f.w);
            *reinterpret_cast<uint2*>(&Bs[r][q * 4]) = cv.u;
        }
        __syncthreads();
        bf16x8 af[4], bfr[4];
#pragma unroll
        for (int mi = 0; mi < 4; mi++)
            af[mi] = *reinterpret_cast<const bf16x8*>(&As[mbase + mi * 16 + lw][lg * 8]);
#pragma unroll
        for (int ni = 0; ni < 4; ni++)
            bfr[ni] = *reinterpret_cast<const bf16x8*>(&Bs[nbase + ni * 16 + lw][lg * 8]);
#pragma unroll
        for (int mi = 0; mi < 4; mi++)
#pragma unroll
            for (int ni = 0; ni < 4; ni++)
                acc[mi][ni] = __builtin_amdgcn_mfma_f32_16x16x32_bf16(af[mi], bfr[ni], acc[mi][ni], 0, 0, 0);
        __syncthreads();
    }

#pragma unroll
    for (int mi = 0; mi < 4; mi++) {
#pragma unroll
        for (int ni = 0; ni < 4; ni++) {
            int colc = col0 + nbase + ni * 16 + lw;
            float bv = bias ? bias[colc] : 0.0f;
#pragma unroll
            for (int j = 0; j < 4; j++) {
                int row = row0 + mbase + mi * 16 + lg * 4 + j;
                size_t off = (size_t)row * N + colc;
                float v = acc[mi][ni][j] + bv;
                if constexpr (EPI == EPI_BF16) {
                    ((u16*)out)[off] = f2bf(v);
                } else if constexpr (EPI == EPI_BF16_GELU) {
                    ((u16*)out)[off] = f2bf(gelu_f(v));
                } else if constexpr (EPI == EPI_F32_RESID) {
                    ((float*)out)[off] = v + resid[off];
                } else {
                    ((float*)out)[off] = v;
                }
            }
        }
    }
}

// ---------------------------------------------------------------- attention
__global__ __launch_bounds__(256) void attn_kernel(
    const u16* __restrict__ qkv, const int* __restrict__ idx, u16* __restrict__ yv)
{
    __shared__ u16 Kt[32][72];
    __shared__ u16 Vt[64][40];
    __shared__ u16 Pb[4][16][40];
    __shared__ int kval[32];

    int tid = threadIdx.x, l = tid & 63, w = tid >> 6;
    int lw = l & 15, lg = l >> 4;
    int bid = blockIdx.x;
    int qb = bid & 15;
    int h = (bid >> 4) % 12;
    int b = bid / (16 * 12);
    const size_t base = (size_t)b * 1024;

    int qrow = qb * 64 + w * 16 + lw;
    const u16* qp = qkv + (base + qrow) * 2304 + h * 64;
    bf16x8 aq0 = *reinterpret_cast<const bf16x8*>(qp + lg * 8);
    bf16x8 aq1 = *reinterpret_cast<const bf16x8*>(qp + 32 + lg * 8);

    int rowj[4], vq[4];
#pragma unroll
    for (int j = 0; j < 4; j++) {
        rowj[j] = qb * 64 + w * 16 + lg * 4 + j;
        vq[j] = idx[base + rowj[j]] > 0;
    }
    float m[4], lsum[4];
    f32x4 O[4] = {};
#pragma unroll
    for (int j = 0; j < 4; j++) { m[j] = -__builtin_inff(); lsum[j] = 0.0f; }

    int kvend = qb * 64 + 64;
    for (int kv0 = 0; kv0 < kvend; kv0 += 32) {
        {
            int r = tid >> 3, cc = tid & 7;
            const u16* kp = qkv + (base + kv0 + r) * 2304 + 768 + h * 64 + cc * 8;
            uint4 ku = *reinterpret_cast<const uint4*>(kp);
            *reinterpret_cast<uint4*>(&Kt[r][cc * 8]) = ku;
            const u16* vp = qkv + (base + kv0 + r) * 2304 + 1536 + h * 64 + cc * 8;
            union { uint4 u; u16 h8[8]; } vu;
            vu.u = *reinterpret_cast<const uint4*>(vp);
#pragma unroll
            for (int j2 = 0; j2 < 8; j2++) Vt[cc * 8 + j2][r] = vu.h8[j2];
            if (tid < 32) kval[tid] = idx[base + kv0 + tid] > 0;
        }
        __syncthreads();

        f32x4 S[2];
#pragma unroll
        for (int g = 0; g < 2; g++) {
            bf16x8 bk0 = *reinterpret_cast<const bf16x8*>(&Kt[g * 16 + lw][lg * 8]);
            bf16x8 bk1 = *reinterpret_cast<const bf16x8*>(&Kt[g * 16 + lw][32 + lg * 8]);
            f32x4 t = {};
            t = __builtin_amdgcn_mfma_f32_16x16x32_bf16(aq0, bk0, t, 0, 0, 0);
            t = __builtin_amdgcn_mfma_f32_16x16x32_bf16(aq1, bk1, t, 0, 0, 0);
            S[g] = t;
        }
        float p[2][4];
#pragma unroll
        for (int j = 0; j < 4; j++) {
            float sv0, sv1;
#pragma unroll
            for (int g = 0; g < 2; g++) {
                int kcol = kv0 + g * 16 + lw;
                float s = S[g][j] * 0.125f;
                bool keep = (kcol <= rowj[j]) &&
                            ((vq[j] && kval[g * 16 + lw]) || (kcol == rowj[j]));
                s = keep ? s : -__builtin_inff();
                if (g) sv1 = s; else sv0 = s;
            }
            float mx = fmaxf(sv0, sv1);
            mx = fmaxf(mx, __shfl_xor(mx, 1));
            mx = fmaxf(mx, __shfl_xor(mx, 2));
            mx = fmaxf(mx, __shfl_xor(mx, 4));
            mx = fmaxf(mx, __shfl_xor(mx, 8));
            float mn = fmaxf(m[j], mx);
            float mclamp = fmaxf(mn, -1e30f);
            float scale = __expf(m[j] - mclamp);
            float p0 = __expf(sv0 - mclamp);
            float p1 = __expf(sv1 - mclamp);
            float rs = p0 + p1;
            rs += __shfl_xor(rs, 1); rs += __shfl_xor(rs, 2);
            rs += __shfl_xor(rs, 4); rs += __shfl_xor(rs, 8);
            lsum[j] = lsum[j] * scale + rs;
            m[j] = mn;
#pragma unroll
            for (int ni = 0; ni < 4; ni++) O[ni][j] *= scale;
            p[0][j] = p0; p[1][j] = p1;
        }
#pragma unroll
        for (int g = 0; g < 2; g++)
#pragma unroll
            for (int j = 0; j < 4; j++)
                Pb[w][lg * 4 + j][g * 16 + lw] = f2bf(p[g][j]);
        bf16x8 ap = *reinterpret_cast<const bf16x8*>(&Pb[w][lw][lg * 8]);
#pragma unroll
        for (int ni = 0; ni < 4; ni++) {
            bf16x8 bv = *reinterpret_cast<const bf16x8*>(&Vt[ni * 16 + lw][lg * 8]);
            O[ni] = __builtin_amdgcn_mfma_f32_16x16x32_bf16(ap, bv, O[ni], 0, 0, 0);
        }
        __syncthreads();
    }

#pragma unroll
    for (int j = 0; j < 4; j++) {
        float inv = 1.0f / lsum[j];
#pragma unroll
        for (int ni = 0; ni < 4; ni++) {
            float v = O[ni][j] * inv;
            yv[(base + rowj[j]) * 768 + h * 64 + ni * 16 + lw] = f2bf(v);
        }
    }
}

// ---------------------------------------------------------------- host
static void launch_gemm_lds(int epi, const u16* A, const u16* B, const float* bias,
                            const float* resid, void* out, int N, int K, hipStream_t s)
{
    int mtiles = 2048 / 128;
    int nwg = mtiles * (N / 128);
    dim3 grid(nwg), blk(256);
    int nwg8 = nwg / 8;
    switch (epi) {
        case EPI_BF16:      gemm_lds_kernel<EPI_BF16><<<grid, blk, 0, s>>>(A, B, bias, resid, out, N, K, mtiles, nwg8); break;
        case EPI_BF16_GELU: gemm_lds_kernel<EPI_BF16_GELU><<<grid, blk, 0, s>>>(A, B, bias, resid, out, N, K, mtiles, nwg8); break;
        case EPI_F32_RESID: gemm_lds_kernel<EPI_F32_RESID><<<grid, blk, 0, s>>>(A, B, bias, resid, out, N, K, mtiles, nwg8); break;
        default:            gemm_lds_kernel<EPI_F32><<<grid, blk, 0, s>>>(A, B, bias, resid, out, N, K, mtiles, nwg8); break;
    }
}

static void launch_gemm_f32w(int epi, const u16* A, const float* Bw, const float* bias,
                             const float* resid, void* out, int N, int K, hipStream_t s)
{
    dim3 grid((2048 / 128) * (N / 128)), blk(256);
    switch (epi) {
        case EPI_BF16:      gemm_kernel<EPI_BF16><<<grid, blk, 0, s>>>(A, Bw, bias, resid, out, N, K); break;
        case EPI_BF16_GELU: gemm_kernel<EPI_BF16_GELU><<<grid, blk, 0, s>>>(A, Bw, bias, resid, out, N, K); break;
        case EPI_F32_RESID: gemm_kernel<EPI_F32_RESID><<<grid, blk, 0, s>>>(A, Bw, bias, resid, out, N, K); break;
        default:            gemm_kernel<EPI_F32><<<grid, blk, 0, s>>>(A, Bw, bias, resid, out, N, K); break;
    }
}

static void cvt(const float* src, u16* dst, size_t n, hipStream_t s) {
    int n4 = (int)(n / 4);
    int blocks = (n4 + 255) / 256;
    if (blocks > 2048) blocks = 2048;
    cvt_kernel<<<blocks, 256, 0, s>>>(src, dst, n4);
}

extern "C" void kernel_launch(void* const* d_in, const int* in_sizes, int n_in,
                              void* d_out, int out_size, void* d_ws, size_t ws_size,
                              hipStream_t stream)
{
    (void)in_sizes; (void)n_in; (void)out_size;
    const int*   idx    = (const int*)  d_in[0];
    const float* age    = (const float*)d_in[1];
    const float* wte    = (const float*)d_in[2];
    const float* wae_w  = (const float*)d_in[3];
    const float* ln1_w  = (const float*)d_in[4];
    const float* ln1_b  = (const float*)d_in[5];
    const float* attn_w = (const float*)d_in[6];
    const float* attn_b = (const float*)d_in[7];
    const float* proj_w = (const float*)d_in[8];
    const float* proj_b = (const float*)d_in[9];
    const float* ln2_w  = (const float*)d_in[10];
    const float* ln2_b  = (const float*)d_in[11];
    const float* fc_w   = (const float*)d_in[12];
    const float* fc_b   = (const float*)d_in[13];
    const float* fc2_w  = (const float*)d_in[14];
    const float* fc2_b  = (const float*)d_in[15];
    const float* lnf_w  = (const float*)d_in[16];
    const float* lnf_b  = (const float*)d_in[17];

    char* ws = (char*)d_ws;
    size_t off = 0;
    float* x   = (float*)(ws + off); off += (size_t)2048 * 768 * 4;
    u16* hb    = (u16*)(ws + off);   off += (size_t)2048 * 768 * 2;
    u16* qkvb  = (u16*)(ws + off);   off += (size_t)2048 * 2304 * 2;
    u16* yvb   = (u16*)(ws + off);   off += (size_t)2048 * 768 * 2;
    u16* a1b   = (u16*)(ws + off);   off += (size_t)2048 * 3072 * 2;
    u16* yage  = (u16*)(ws + off);   off += (size_t)2048 * 768 * 2;
    // bf16 weight mirrors
    u16* wte_b  = (u16*)(ws + off);  off += (size_t)32768 * 768 * 2;
    u16* attn_wb= (u16*)(ws + off);  off += (size_t)4 * 2304 * 768 * 2;
    u16* proj_wb= (u16*)(ws + off);  off += (size_t)4 * 768 * 768 * 2;
    u16* fc_wb  = (u16*)(ws + off);  off += (size_t)4 * 3072 * 768 * 2;
    u16* fc2_wb = (u16*)(ws + off);  off += (size_t)4 * 768 * 3072 * 2;
    u16* wae_wb = (u16*)(ws + off);  off += (size_t)768 * 768 * 2;
    const size_t NEED = off;

    if (ws_size >= NEED) {
        cvt(wte,    wte_b,   (size_t)32768 * 768, stream);
        cvt(attn_w, attn_wb, (size_t)4 * 2304 * 768, stream);
        cvt(proj_w, proj_wb, (size_t)4 * 768 * 768, stream);
        cvt(fc_w,   fc_wb,   (size_t)4 * 3072 * 768, stream);
        cvt(fc2_w,  fc2_wb,  (size_t)4 * 768 * 3072, stream);
        cvt(wae_w,  wae_wb,  (size_t)768 * 768, stream);

        embed_kernel<<<2048, 256, 0, stream>>>(idx, age, wte, x, yage);
        launch_gemm_lds(EPI_F32_RESID, yage, wae_wb, nullptr, x, x, 768, 768, stream);

        for (int li = 0; li < 4; li++) {
            ln_kernel<<<2048, 256, 0, stream>>>(x, ln1_w + li * 768, ln1_b + li * 768, hb);
            launch_gemm_lds(EPI_BF16, hb, attn_wb + (size_t)li * 2304 * 768, attn_b + li * 2304,
                            nullptr, qkvb, 2304, 768, stream);
            attn_kernel<<<2 * 12 * 16, 256, 0, stream>>>(qkvb, idx, yvb);
            launch_gemm_lds(EPI_F32_RESID, yvb, proj_wb + (size_t)li * 768 * 768, proj_b + li * 768,
                            x, x, 768, 768, stream);
            ln_kernel<<<2048, 256, 0, stream>>>(x, ln2_w + li * 768, ln2_b + li * 768, hb);
            launch_gemm_lds(EPI_BF16_GELU, hb, fc_wb + (size_t)li * 3072 * 768, fc_b + li * 3072,
                            nullptr, a1b, 3072, 768, stream);
            launch_gemm_lds(EPI_F32_RESID, a1b, fc2_wb + (size_t)li * 768 * 3072, fc2_b + li * 768,
                            x, x, 768, 3072, stream);
        }

        ln_kernel<<<2048, 256, 0, stream>>>(x, lnf_w, lnf_b, hb);
        launch_gemm_lds(EPI_F32, hb, wte_b, nullptr, nullptr, d_out, 32768, 768, stream);
    } else {
        // fallback: fp32-weight path (round-1)
        embed_kernel<<<2048, 256, 0, stream>>>(idx, age, wte, x, yage);
        launch_gemm_f32w(EPI_F32_RESID, yage, wae_w, nullptr, x, x, 768, 768, stream);
        for (int li = 0; li < 4; li++) {
            ln_kernel<<<2048, 256, 0, stream>>>(x, ln1_w + li * 768, ln1_b + li * 768, hb);
            launch_gemm_f32w(EPI_BF16, hb, attn_w + (size_t)li * 2304 * 768, attn_b + li * 2304,
                             nullptr, qkvb, 2304, 768, stream);
            attn_kernel<<<2 * 12 * 16, 256, 0, stream>>>(qkvb, idx, yvb);
            launch_gemm_f32w(EPI_F32_RESID, yvb, proj_w + (size_t)li * 768 * 768, proj_b + li * 768,
                             x, x, 768, 768, stream);
            ln_kernel<<<2048, 256, 0, stream>>>(x, ln2_w + li * 768, ln2_b + li * 768, hb);
            launch_gemm_f32w(EPI_BF16_GELU, hb, fc_w + (size_t)li * 3072 * 768, fc_b + li * 3072,
                             nullptr, a1b, 3072, 768, stream);
            launch_gemm_f32w(EPI_F32_RESID, a1b, fc2_w + (size_t)li * 768 * 3072, fc2_b + li * 768,
                             x, x, 768, 3072, stream);
        }
        ln_kernel<<<2048, 256, 0, stream>>>(x, lnf_w, lnf_b, hb);
        launch_gemm_f32w(EPI_F32, hb, wte, nullptr, nullptr, d_out, 32768, 768, stream);
    }
}

// Round 5
// 1553.339 us; speedup vs baseline: 1.3267x; 1.1318x over previous
//
#include <hip/hip_runtime.h>

typedef unsigned short u16;
typedef __bf16 bf16x8 __attribute__((ext_vector_type(8)));
typedef float f32x4 __attribute__((ext_vector_type(4)));

// fp32 -> bf16 round-to-nearest-even
__device__ __forceinline__ u16 f2bf(float f) {
    union { float f; unsigned int u; } c; c.f = f;
    unsigned int u = c.u;
    unsigned int r = (u + 0x7FFFu + ((u >> 16) & 1u)) >> 16;
    return (u16)r;
}

__device__ __forceinline__ float gelu_f(float v) {
    const float c = 0.7978845608028654f;
    float t = tanhf(c * (v + 0.044715f * v * v * v));
    return 0.5f * v * (1.0f + t);
}

typedef const __attribute__((address_space(1))) unsigned int* as1_u32p;
typedef __attribute__((address_space(3))) unsigned int* as3_u32p;
__device__ __forceinline__ void gload16(const void* g, void* l) {
    __builtin_amdgcn_global_load_lds((as1_u32p)g, (as3_u32p)l, 16, 0, 0);
}

// ---------------------------------------------------------------- weight convert
__global__ __launch_bounds__(256) void cvt_kernel(
    const float* __restrict__ src, u16* __restrict__ dst, int n4)
{
    int i = blockIdx.x * 256 + threadIdx.x;
    int stride = gridDim.x * 256;
    for (; i < n4; i += stride) {
        float4 f = reinterpret_cast<const float4*>(src)[i];
        union { u16 h[4]; uint2 u; } cv;
        cv.h[0] = f2bf(f.x); cv.h[1] = f2bf(f.y);
        cv.h[2] = f2bf(f.z); cv.h[3] = f2bf(f.w);
        reinterpret_cast<uint2*>(dst)[i] = cv.u;
    }
}

// ---------------------------------------------------------------- embedding
__global__ __launch_bounds__(256) void embed_kernel(
    const int* __restrict__ idx, const float* __restrict__ age,
    const float* __restrict__ wte, float* __restrict__ x, u16* __restrict__ y)
{
    int t = blockIdx.x;
    int tid = threadIdx.x;
    int tok = idx[t];
    float a = age[t] * (1.0f / 365.25f);
    const float kc = -9.210340371976184f / 768.0f;   // -ln(10000)/D
#pragma unroll
    for (int j = 0; j < 3; j++) {
        int d = tid + j * 256;
        x[(size_t)t * 768 + d] = wte[(size_t)tok * 768 + d];
        int twoi = d & ~1;
        float dv = __expf(kc * (float)twoi);
        float ang = a * dv;
        float val = (d & 1) ? __cosf(ang) : __sinf(ang);
        y[(size_t)t * 768 + d] = f2bf(val);
    }
}

// ---------------------------------------------------------------- layernorm
__global__ __launch_bounds__(256) void ln_kernel(
    const float* __restrict__ x, const float* __restrict__ w,
    const float* __restrict__ b, u16* __restrict__ out)
{
    int row = blockIdx.x;
    int tid = threadIdx.x;
    int l = tid & 63, wv = tid >> 6;
    const float* xr = x + (size_t)row * 768;
    float v[3], s = 0.f, ss = 0.f;
#pragma unroll
    for (int j = 0; j < 3; j++) { v[j] = xr[tid + j * 256]; s += v[j]; ss += v[j] * v[j]; }
#pragma unroll
    for (int d = 1; d < 64; d <<= 1) { s += __shfl_xor(s, d); ss += __shfl_xor(ss, d); }
    __shared__ float ps[4], pss[4];
    if (l == 0) { ps[wv] = s; pss[wv] = ss; }
    __syncthreads();
    s = ps[0] + ps[1] + ps[2] + ps[3];
    ss = pss[0] + pss[1] + pss[2] + pss[3];
    float mu = s * (1.0f / 768.0f);
    float var = ss * (1.0f / 768.0f) - mu * mu;
    float rstd = rsqrtf(var + 1e-5f);
#pragma unroll
    for (int j = 0; j < 3; j++) {
        int d = tid + j * 256;
        out[(size_t)row * 768 + d] = f2bf((v[j] - mu) * rstd * w[d] + b[d]);
    }
}

// ---------------------------------------------------------------- GEMM (double-buffered, single barrier/iter)
// C[M=2048,N] = A[M,K](bf16) @ B[N,K](bf16)^T + bias ; XCD-swizzled grid, mt fastest
// BM=128: waves 2x2 (64x64 each, acc 4x4). BM=64: waves 1x4 (64x32 each, acc 4x2).
enum { EPI_BF16 = 0, EPI_BF16_GELU = 1, EPI_F32_RESID = 2, EPI_F32 = 3 };

template <int EPI, int BM, int NWM>
__global__ __launch_bounds__(256) void gemm_db_kernel(
    const u16* __restrict__ A, const u16* __restrict__ B,
    const float* __restrict__ bias, const float* resid, void* out,
    int N, int K, int mtiles, int nwg8)
{
    constexpr int NWN = 4 / NWM;
    constexpr int MI  = (BM / NWM) / 16;
    constexpr int NI  = (128 / NWN) / 16;
    constexpr int ASHOTS = (BM * 4) / 256;   // 16B chunks/thread for the A tile
    __shared__ u16 As[2][BM][32];
    __shared__ u16 Bs[2][128][32];
    int tid = threadIdx.x;
    int l = tid & 63, w = tid >> 6;
    int lw = l & 15, lg = l >> 4;
    int bid = blockIdx.x;
    int wg = (bid & 7) * nwg8 + (bid >> 3);   // bijective XCD swizzle (nwg%8==0)
    int mt = wg % mtiles, nt = wg / mtiles;
    int row0 = mt * BM, col0 = nt * 128;
    int wm = w % NWM, wn = w / NWM;
    int mbase = wm * (BM / NWM), nbase = wn * (128 / NWN);

    f32x4 acc[MI][NI] = {};
    const int ntiles = K >> 5;

    auto stage = [&](int nb, int kk) {
        u16* asb = &As[nb][0][0];
        u16* bsb = &Bs[nb][0][0];
#pragma unroll
        for (int s = 0; s < ASHOTS; s++) {
            int c = s * 256 + tid;
            int r = c >> 2, q = (c & 3) * 8;
            gload16(A + (size_t)(row0 + r) * K + kk + q, asb + r * 32 + q);
        }
#pragma unroll
        for (int s = 0; s < 2; s++) {
            int c = s * 256 + tid;
            int r = c >> 2, q = (c & 3) * 8;
            gload16(B + (size_t)(col0 + r) * K + kk + q, bsb + r * 32 + q);
        }
    };

    stage(0, 0);
    __syncthreads();                       // vmcnt(0) drain of prologue loads
    for (int t = 0; t < ntiles; ++t) {
        int cur = t & 1;
        if (t + 1 < ntiles) stage(cur ^ 1, (t + 1) << 5);   // prefetch next tile
        bf16x8 af[MI], bfr[NI];
#pragma unroll
        for (int mi = 0; mi < MI; mi++)
            af[mi] = *reinterpret_cast<const bf16x8*>(&As[cur][mbase + mi * 16 + lw][lg * 8]);
#pragma unroll
        for (int ni = 0; ni < NI; ni++)
            bfr[ni] = *reinterpret_cast<const bf16x8*>(&Bs[cur][nbase + ni * 16 + lw][lg * 8]);
        __builtin_amdgcn_s_setprio(1);
#pragma unroll
        for (int mi = 0; mi < MI; mi++)
#pragma unroll
            for (int ni = 0; ni < NI; ni++)
                acc[mi][ni] = __builtin_amdgcn_mfma_f32_16x16x32_bf16(af[mi], bfr[ni], acc[mi][ni], 0, 0, 0);
        __builtin_amdgcn_s_setprio(0);
        __syncthreads();                   // drains prefetch loads AFTER compute
    }

#pragma unroll
    for (int mi = 0; mi < MI; mi++) {
#pragma unroll
        for (int ni = 0; ni < NI; ni++) {
            int colc = col0 + nbase + ni * 16 + lw;
            float bv = bias ? bias[colc] : 0.0f;
#pragma unroll
            for (int j = 0; j < 4; j++) {
                int row = row0 + mbase + mi * 16 + lg * 4 + j;
                size_t off = (size_t)row * N + colc;
                float v = acc[mi][ni][j] + bv;
                if constexpr (EPI == EPI_BF16) {
                    ((u16*)out)[off] = f2bf(v);
                } else if constexpr (EPI == EPI_BF16_GELU) {
                    ((u16*)out)[off] = f2bf(gelu_f(v));
                } else if constexpr (EPI == EPI_F32_RESID) {
                    ((float*)out)[off] = v + resid[off];
                } else {
                    ((float*)out)[off] = v;
                }
            }
        }
    }
}

// ---------------------------------------------------------------- GEMM fallback (fp32 weights)
template <int EPI>
__global__ __launch_bounds__(256) void gemm_kernel(
    const u16* __restrict__ A, const float* __restrict__ Bw,
    const float* __restrict__ bias, const float* resid, void* out,
    int N, int K)
{
    constexpr int M = 2048;
    __shared__ u16 As[128][40];
    __shared__ u16 Bs[128][40];
    int tid = threadIdx.x;
    int l = tid & 63, w = tid >> 6;
    int lw = l & 15, lg = l >> 4;
    int mtiles = M / 128;
    int mt = blockIdx.x % mtiles, nt = blockIdx.x / mtiles;
    int row0 = mt * 128, col0 = nt * 128;
    int mbase = (w & 1) * 64, nbase = (w >> 1) * 64;
    f32x4 acc[4][4] = {};

    for (int kk = 0; kk < K; kk += 32) {
        int c = tid;
#pragma unroll
        for (int i = 0; i < 2; i++, c += 256) {
            int r = c >> 2, q = c & 3;
            uint4 u = *reinterpret_cast<const uint4*>(A + (size_t)(row0 + r) * K + kk + q * 8);
            *reinterpret_cast<uint4*>(&As[r][q * 8]) = u;
        }
        int c2 = tid;
#pragma unroll
        for (int i = 0; i < 4; i++, c2 += 256) {
            int r = c2 >> 3, q = c2 & 7;
            const float4 f = *reinterpret_cast<const float4*>(Bw + (size_t)(col0 + r) * K + kk + q * 4);
            union { u16 h[4]; uint2 u; } cv;
            cv.h[0] = f2bf(f.x); cv.h[1] = f2bf(f.y); cv.h[2] = f2bf(f.z); cv.h[3] = f2bf(f.w);
            *reinterpret_cast<uint2*>(&Bs[r][q * 4]) = cv.u;
        }
        __syncthreads();
        bf16x8 af[4], bfr[4];
#pragma unroll
        for (int mi = 0; mi < 4; mi++)
            af[mi] = *reinterpret_cast<const bf16x8*>(&As[mbase + mi * 16 + lw][lg * 8]);
#pragma unroll
        for (int ni = 0; ni < 4; ni++)
            bfr[ni] = *reinterpret_cast<const bf16x8*>(&Bs[nbase + ni * 16 + lw][lg * 8]);
#pragma unroll
        for (int mi = 0; mi < 4; mi++)
#pragma unroll
            for (int ni = 0; ni < 4; ni++)
                acc[mi][ni] = __builtin_amdgcn_mfma_f32_16x16x32_bf16(af[mi], bfr[ni], acc[mi][ni], 0, 0, 0);
        __syncthreads();
    }

#pragma unroll
    for (int mi = 0; mi < 4; mi++) {
#pragma unroll
        for (int ni = 0; ni < 4; ni++) {
            int colc = col0 + nbase + ni * 16 + lw;
            float bv = bias ? bias[colc] : 0.0f;
#pragma unroll
            for (int j = 0; j < 4; j++) {
                int row = row0 + mbase + mi * 16 + lg * 4 + j;
                size_t off = (size_t)row * N + colc;
                float v = acc[mi][ni][j] + bv;
                if constexpr (EPI == EPI_BF16) {
                    ((u16*)out)[off] = f2bf(v);
                } else if constexpr (EPI == EPI_BF16_GELU) {
                    ((u16*)out)[off] = f2bf(gelu_f(v));
                } else if constexpr (EPI == EPI_F32_RESID) {
                    ((float*)out)[off] = v + resid[off];
                } else {
                    ((float*)out)[off] = v;
                }
            }
        }
    }
}

// ---------------------------------------------------------------- attention
__global__ __launch_bounds__(256) void attn_kernel(
    const u16* __restrict__ qkv, const int* __restrict__ idx, u16* __restrict__ yv)
{
    __shared__ u16 Kt[32][72];
    __shared__ u16 Vt[64][40];
    __shared__ u16 Pb[4][16][40];
    __shared__ int kval[32];

    int tid = threadIdx.x, l = tid & 63, w = tid >> 6;
    int lw = l & 15, lg = l >> 4;
    int bid = blockIdx.x;
    int qb = bid & 15;
    int h = (bid >> 4) % 12;
    int b = bid / (16 * 12);
    const size_t base = (size_t)b * 1024;

    int qrow = qb * 64 + w * 16 + lw;
    const u16* qp = qkv + (base + qrow) * 2304 + h * 64;
    bf16x8 aq0 = *reinterpret_cast<const bf16x8*>(qp + lg * 8);
    bf16x8 aq1 = *reinterpret_cast<const bf16x8*>(qp + 32 + lg * 8);

    int rowj[4], vq[4];
#pragma unroll
    for (int j = 0; j < 4; j++) {
        rowj[j] = qb * 64 + w * 16 + lg * 4 + j;
        vq[j] = idx[base + rowj[j]] > 0;
    }
    float m[4], lsum[4];
    f32x4 O[4] = {};
#pragma unroll
    for (int j = 0; j < 4; j++) { m[j] = -__builtin_inff(); lsum[j] = 0.0f; }

    int kvend = qb * 64 + 64;
    for (int kv0 = 0; kv0 < kvend; kv0 += 32) {
        {
            int r = tid >> 3, cc = tid & 7;
            const u16* kp = qkv + (base + kv0 + r) * 2304 + 768 + h * 64 + cc * 8;
            uint4 ku = *reinterpret_cast<const uint4*>(kp);
            *reinterpret_cast<uint4*>(&Kt[r][cc * 8]) = ku;
            const u16* vp = qkv + (base + kv0 + r) * 2304 + 1536 + h * 64 + cc * 8;
            union { uint4 u; u16 h8[8]; } vu;
            vu.u = *reinterpret_cast<const uint4*>(vp);
#pragma unroll
            for (int j2 = 0; j2 < 8; j2++) Vt[cc * 8 + j2][r] = vu.h8[j2];
            if (tid < 32) kval[tid] = idx[base + kv0 + tid] > 0;
        }
        __syncthreads();

        f32x4 S[2];
#pragma unroll
        for (int g = 0; g < 2; g++) {
            bf16x8 bk0 = *reinterpret_cast<const bf16x8*>(&Kt[g * 16 + lw][lg * 8]);
            bf16x8 bk1 = *reinterpret_cast<const bf16x8*>(&Kt[g * 16 + lw][32 + lg * 8]);
            f32x4 t = {};
            t = __builtin_amdgcn_mfma_f32_16x16x32_bf16(aq0, bk0, t, 0, 0, 0);
            t = __builtin_amdgcn_mfma_f32_16x16x32_bf16(aq1, bk1, t, 0, 0, 0);
            S[g] = t;
        }
        float p[2][4];
#pragma unroll
        for (int j = 0; j < 4; j++) {
            float sv0, sv1;
#pragma unroll
            for (int g = 0; g < 2; g++) {
                int kcol = kv0 + g * 16 + lw;
                float s = S[g][j] * 0.125f;
                bool keep = (kcol <= rowj[j]) &&
                            ((vq[j] && kval[g * 16 + lw]) || (kcol == rowj[j]));
                s = keep ? s : -__builtin_inff();
                if (g) sv1 = s; else sv0 = s;
            }
            float mx = fmaxf(sv0, sv1);
            mx = fmaxf(mx, __shfl_xor(mx, 1));
            mx = fmaxf(mx, __shfl_xor(mx, 2));
            mx = fmaxf(mx, __shfl_xor(mx, 4));
            mx = fmaxf(mx, __shfl_xor(mx, 8));
            float mn = fmaxf(m[j], mx);
            float mclamp = fmaxf(mn, -1e30f);
            float scale = __expf(m[j] - mclamp);
            float p0 = __expf(sv0 - mclamp);
            float p1 = __expf(sv1 - mclamp);
            float rs = p0 + p1;
            rs += __shfl_xor(rs, 1); rs += __shfl_xor(rs, 2);
            rs += __shfl_xor(rs, 4); rs += __shfl_xor(rs, 8);
            lsum[j] = lsum[j] * scale + rs;
            m[j] = mn;
#pragma unroll
            for (int ni = 0; ni < 4; ni++) O[ni][j] *= scale;
            p[0][j] = p0; p[1][j] = p1;
        }
#pragma unroll
        for (int g = 0; g < 2; g++)
#pragma unroll
            for (int j = 0; j < 4; j++)
                Pb[w][lg * 4 + j][g * 16 + lw] = f2bf(p[g][j]);
        bf16x8 ap = *reinterpret_cast<const bf16x8*>(&Pb[w][lw][lg * 8]);
#pragma unroll
        for (int ni = 0; ni < 4; ni++) {
            bf16x8 bv = *reinterpret_cast<const bf16x8*>(&Vt[ni * 16 + lw][lg * 8]);
            O[ni] = __builtin_amdgcn_mfma_f32_16x16x32_bf16(ap, bv, O[ni], 0, 0, 0);
        }
        __syncthreads();
    }

#pragma unroll
    for (int j = 0; j < 4; j++) {
        float inv = 1.0f / lsum[j];
#pragma unroll
        for (int ni = 0; ni < 4; ni++) {
            float v = O[ni][j] * inv;
            yv[(base + rowj[j]) * 768 + h * 64 + ni * 16 + lw] = f2bf(v);
        }
    }
}

// ---------------------------------------------------------------- host
// BM=64 for N=768 (more workgroups on 256 CUs), BM=128 otherwise.
static void launch_gemm_db(int epi, const u16* A, const u16* B, const float* bias,
                           const float* resid, void* out, int N, int K, hipStream_t s)
{
    dim3 blk(256);
    if (N == 768) {
        constexpr int BM = 64, NWM = 1;
        int mtiles = 2048 / BM;
        int nwg = mtiles * (N / 128);
        dim3 grid(nwg);
        int nwg8 = nwg / 8;
        switch (epi) {
            case EPI_BF16:      gemm_db_kernel<EPI_BF16, BM, NWM><<<grid, blk, 0, s>>>(A, B, bias, resid, out, N, K, mtiles, nwg8); break;
            case EPI_BF16_GELU: gemm_db_kernel<EPI_BF16_GELU, BM, NWM><<<grid, blk, 0, s>>>(A, B, bias, resid, out, N, K, mtiles, nwg8); break;
            case EPI_F32_RESID: gemm_db_kernel<EPI_F32_RESID, BM, NWM><<<grid, blk, 0, s>>>(A, B, bias, resid, out, N, K, mtiles, nwg8); break;
            default:            gemm_db_kernel<EPI_F32, BM, NWM><<<grid, blk, 0, s>>>(A, B, bias, resid, out, N, K, mtiles, nwg8); break;
        }
    } else {
        constexpr int BM = 128, NWM = 2;
        int mtiles = 2048 / BM;
        int nwg = mtiles * (N / 128);
        dim3 grid(nwg);
        int nwg8 = nwg / 8;
        switch (epi) {
            case EPI_BF16:      gemm_db_kernel<EPI_BF16, BM, NWM><<<grid, blk, 0, s>>>(A, B, bias, resid, out, N, K, mtiles, nwg8); break;
            case EPI_BF16_GELU: gemm_db_kernel<EPI_BF16_GELU, BM, NWM><<<grid, blk, 0, s>>>(A, B, bias, resid, out, N, K, mtiles, nwg8); break;
            case EPI_F32_RESID: gemm_db_kernel<EPI_F32_RESID, BM, NWM><<<grid, blk, 0, s>>>(A, B, bias, resid, out, N, K, mtiles, nwg8); break;
            default:            gemm_db_kernel<EPI_F32, BM, NWM><<<grid, blk, 0, s>>>(A, B, bias, resid, out, N, K, mtiles, nwg8); break;
        }
    }
}

static void launch_gemm_f32w(int epi, const u16* A, const float* Bw, const float* bias,
                             const float* resid, void* out, int N, int K, hipStream_t s)
{
    dim3 grid((2048 / 128) * (N / 128)), blk(256);
    switch (epi) {
        case EPI_BF16:      gemm_kernel<EPI_BF16><<<grid, blk, 0, s>>>(A, Bw, bias, resid, out, N, K); break;
        case EPI_BF16_GELU: gemm_kernel<EPI_BF16_GELU><<<grid, blk, 0, s>>>(A, Bw, bias, resid, out, N, K); break;
        case EPI_F32_RESID: gemm_kernel<EPI_F32_RESID><<<grid, blk, 0, s>>>(A, Bw, bias, resid, out, N, K); break;
        default:            gemm_kernel<EPI_F32><<<grid, blk, 0, s>>>(A, Bw, bias, resid, out, N, K); break;
    }
}

static void cvt(const float* src, u16* dst, size_t n, hipStream_t s) {
    int n4 = (int)(n / 4);
    int blocks = (n4 + 255) / 256;
    if (blocks > 2048) blocks = 2048;
    cvt_kernel<<<blocks, 256, 0, s>>>(src, dst, n4);
}

extern "C" void kernel_launch(void* const* d_in, const int* in_sizes, int n_in,
                              void* d_out, int out_size, void* d_ws, size_t ws_size,
                              hipStream_t stream)
{
    (void)in_sizes; (void)n_in; (void)out_size;
    const int*   idx    = (const int*)  d_in[0];
    const float* age    = (const float*)d_in[1];
    const float* wte    = (const float*)d_in[2];
    const float* wae_w  = (const float*)d_in[3];
    const float* ln1_w  = (const float*)d_in[4];
    const float* ln1_b  = (const float*)d_in[5];
    const float* attn_w = (const float*)d_in[6];
    const float* attn_b = (const float*)d_in[7];
    const float* proj_w = (const float*)d_in[8];
    const float* proj_b = (const float*)d_in[9];
    const float* ln2_w  = (const float*)d_in[10];
    const float* ln2_b  = (const float*)d_in[11];
    const float* fc_w   = (const float*)d_in[12];
    const float* fc_b   = (const float*)d_in[13];
    const float* fc2_w  = (const float*)d_in[14];
    const float* fc2_b  = (const float*)d_in[15];
    const float* lnf_w  = (const float*)d_in[16];
    const float* lnf_b  = (const float*)d_in[17];

    char* ws = (char*)d_ws;
    size_t off = 0;
    float* x   = (float*)(ws + off); off += (size_t)2048 * 768 * 4;
    u16* hb    = (u16*)(ws + off);   off += (size_t)2048 * 768 * 2;
    u16* qkvb  = (u16*)(ws + off);   off += (size_t)2048 * 2304 * 2;
    u16* yvb   = (u16*)(ws + off);   off += (size_t)2048 * 768 * 2;
    u16* a1b   = (u16*)(ws + off);   off += (size_t)2048 * 3072 * 2;
    u16* yage  = (u16*)(ws + off);   off += (size_t)2048 * 768 * 2;
    // bf16 weight mirrors
    u16* wte_b  = (u16*)(ws + off);  off += (size_t)32768 * 768 * 2;
    u16* attn_wb= (u16*)(ws + off);  off += (size_t)4 * 2304 * 768 * 2;
    u16* proj_wb= (u16*)(ws + off);  off += (size_t)4 * 768 * 768 * 2;
    u16* fc_wb  = (u16*)(ws + off);  off += (size_t)4 * 3072 * 768 * 2;
    u16* fc2_wb = (u16*)(ws + off);  off += (size_t)4 * 768 * 3072 * 2;
    u16* wae_wb = (u16*)(ws + off);  off += (size_t)768 * 768 * 2;
    const size_t NEED = off;

    if (ws_size >= NEED) {
        cvt(wte,    wte_b,   (size_t)32768 * 768, stream);
        cvt(attn_w, attn_wb, (size_t)4 * 2304 * 768, stream);
        cvt(proj_w, proj_wb, (size_t)4 * 768 * 768, stream);
        cvt(fc_w,   fc_wb,   (size_t)4 * 3072 * 768, stream);
        cvt(fc2_w,  fc2_wb,  (size_t)4 * 768 * 3072, stream);
        cvt(wae_w,  wae_wb,  (size_t)768 * 768, stream);

        embed_kernel<<<2048, 256, 0, stream>>>(idx, age, wte, x, yage);
        launch_gemm_db(EPI_F32_RESID, yage, wae_wb, nullptr, x, x, 768, 768, stream);

        for (int li = 0; li < 4; li++) {
            ln_kernel<<<2048, 256, 0, stream>>>(x, ln1_w + li * 768, ln1_b + li * 768, hb);
            launch_gemm_db(EPI_BF16, hb, attn_wb + (size_t)li * 2304 * 768, attn_b + li * 2304,
                           nullptr, qkvb, 2304, 768, stream);
            attn_kernel<<<2 * 12 * 16, 256, 0, stream>>>(qkvb, idx, yvb);
            launch_gemm_db(EPI_F32_RESID, yvb, proj_wb + (size_t)li * 768 * 768, proj_b + li * 768,
                           x, x, 768, 768, stream);
            ln_kernel<<<2048, 256, 0, stream>>>(x, ln2_w + li * 768, ln2_b + li * 768, hb);
            launch_gemm_db(EPI_BF16_GELU, hb, fc_wb + (size_t)li * 3072 * 768, fc_b + li * 3072,
                           nullptr, a1b, 3072, 768, stream);
            launch_gemm_db(EPI_F32_RESID, a1b, fc2_wb + (size_t)li * 768 * 3072, fc2_b + li * 768,
                           x, x, 768, 3072, stream);
        }

        ln_kernel<<<2048, 256, 0, stream>>>(x, lnf_w, lnf_b, hb);
        launch_gemm_db(EPI_F32, hb, wte_b, nullptr, nullptr, d_out, 32768, 768, stream);
    } else {
        // fallback: fp32-weight path
        embed_kernel<<<2048, 256, 0, stream>>>(idx, age, wte, x, yage);
        launch_gemm_f32w(EPI_F32_RESID, yage, wae_w, nullptr, x, x, 768, 768, stream);
        for (int li = 0; li < 4; li++) {
            ln_kernel<<<2048, 256, 0, stream>>>(x, ln1_w + li * 768, ln1_b + li * 768, hb);
            launch_gemm_f32w(EPI_BF16, hb, attn_w + (size_t)li * 2304 * 768, attn_b + li * 2304,
                             nullptr, qkvb, 2304, 768, stream);
            attn_kernel<<<2 * 12 * 16, 256, 0, stream>>>(qkvb, idx, yvb);
            launch_gemm_f32w(EPI_F32_RESID, yvb, proj_w + (size_t)li * 768 * 768, proj_b + li * 768,
                             x, x, 768, 768, stream);
            ln_kernel<<<2048, 256, 0, stream>>>(x, ln2_w + li * 768, ln2_b + li * 768, hb);
            launch_gemm_f32w(EPI_BF16_GELU, hb, fc_w + (size_t)li * 3072 * 768, fc_b + li * 3072,
                             nullptr, a1b, 3072, 768, stream);
            launch_gemm_f32w(EPI_F32_RESID, a1b, fc2_w + (size_t)li * 768 * 3072, fc2_b + li * 768,
                             x, x, 768, 3072, stream);
        }
        ln_kernel<<<2048, 256, 0, stream>>>(x, lnf_w, lnf_b, hb);
        launch_gemm_f32w(EPI_F32, hb, wte, nullptr, nullptr, d_out, 32768, 768, stream);
    }
}

// Round 6
// 1552.179 us; speedup vs baseline: 1.3277x; 1.0007x over previous
//
#include <hip/hip_runtime.h>

typedef unsigned short u16;
typedef __bf16 bf16x8 __attribute__((ext_vector_type(8)));
typedef float f32x4 __attribute__((ext_vector_type(4)));

// fp32 -> bf16 round-to-nearest-even
__device__ __forceinline__ u16 f2bf(float f) {
    union { float f; unsigned int u; } c; c.f = f;
    unsigned int u = c.u;
    unsigned int r = (u + 0x7FFFu + ((u >> 16) & 1u)) >> 16;
    return (u16)r;
}

__device__ __forceinline__ float gelu_f(float v) {
    const float c = 0.7978845608028654f;
    float t = tanhf(c * (v + 0.044715f * v * v * v));
    return 0.5f * v * (1.0f + t);
}

typedef const __attribute__((address_space(1))) unsigned int* as1_u32p;
typedef __attribute__((address_space(3))) unsigned int* as3_u32p;
__device__ __forceinline__ void gload16(const void* g, void* l) {
    __builtin_amdgcn_global_load_lds((as1_u32p)g, (as3_u32p)l, 16, 0, 0);
}

template <int N> __device__ __forceinline__ void wait_vmcnt() {
    if constexpr (N == 0)      asm volatile("s_waitcnt vmcnt(0)" ::: "memory");
    else if constexpr (N == 3) asm volatile("s_waitcnt vmcnt(3)" ::: "memory");
    else if constexpr (N == 4) asm volatile("s_waitcnt vmcnt(4)" ::: "memory");
    else if constexpr (N == 6) asm volatile("s_waitcnt vmcnt(6)" ::: "memory");
    else if constexpr (N == 8) asm volatile("s_waitcnt vmcnt(8)" ::: "memory");
}

// ---------------------------------------------------------------- weight convert
__global__ __launch_bounds__(256) void cvt_kernel(
    const float* __restrict__ src, u16* __restrict__ dst, int n4)
{
    int i = blockIdx.x * 256 + threadIdx.x;
    int stride = gridDim.x * 256;
    for (; i < n4; i += stride) {
        float4 f = reinterpret_cast<const float4*>(src)[i];
        union { u16 h[4]; uint2 u; } cv;
        cv.h[0] = f2bf(f.x); cv.h[1] = f2bf(f.y);
        cv.h[2] = f2bf(f.z); cv.h[3] = f2bf(f.w);
        reinterpret_cast<uint2*>(dst)[i] = cv.u;
    }
}

// ---------------------------------------------------------------- embedding
__global__ __launch_bounds__(256) void embed_kernel(
    const int* __restrict__ idx, const float* __restrict__ age,
    const float* __restrict__ wte, float* __restrict__ x, u16* __restrict__ y)
{
    int t = blockIdx.x;
    int tid = threadIdx.x;
    int tok = idx[t];
    float a = age[t] * (1.0f / 365.25f);
    const float kc = -9.210340371976184f / 768.0f;   // -ln(10000)/D
#pragma unroll
    for (int j = 0; j < 3; j++) {
        int d = tid + j * 256;
        x[(size_t)t * 768 + d] = wte[(size_t)tok * 768 + d];
        int twoi = d & ~1;
        float dv = __expf(kc * (float)twoi);
        float ang = a * dv;
        float val = (d & 1) ? __cosf(ang) : __sinf(ang);
        y[(size_t)t * 768 + d] = f2bf(val);
    }
}

// ---------------------------------------------------------------- layernorm
__global__ __launch_bounds__(256) void ln_kernel(
    const float* __restrict__ x, const float* __restrict__ w,
    const float* __restrict__ b, u16* __restrict__ out)
{
    int row = blockIdx.x;
    int tid = threadIdx.x;
    int l = tid & 63, wv = tid >> 6;
    const float* xr = x + (size_t)row * 768;
    float v[3], s = 0.f, ss = 0.f;
#pragma unroll
    for (int j = 0; j < 3; j++) { v[j] = xr[tid + j * 256]; s += v[j]; ss += v[j] * v[j]; }
#pragma unroll
    for (int d = 1; d < 64; d <<= 1) { s += __shfl_xor(s, d); ss += __shfl_xor(ss, d); }
    __shared__ float ps[4], pss[4];
    if (l == 0) { ps[wv] = s; pss[wv] = ss; }
    __syncthreads();
    s = ps[0] + ps[1] + ps[2] + ps[3];
    ss = pss[0] + pss[1] + pss[2] + pss[3];
    float mu = s * (1.0f / 768.0f);
    float var = ss * (1.0f / 768.0f) - mu * mu;
    float rstd = rsqrtf(var + 1e-5f);
#pragma unroll
    for (int j = 0; j < 3; j++) {
        int d = tid + j * 256;
        out[(size_t)row * 768 + d] = f2bf((v[j] - mu) * rstd * w[d] + b[d]);
    }
}

// ---------------------------------------------------------------- GEMM (depth-3 counted-vmcnt pipeline)
// C[M=2048,N] = A[M,K](bf16) @ B[N,K](bf16)^T + bias ; XCD-swizzled grid, mt fastest.
// 4 LDS buffers; stage(t+3) issued each iter; s_waitcnt vmcnt(2*LPS) + raw s_barrier
// per iter (never drains to 0 mid-loop). Hazards: RAW by counted wait+barrier; WAR
// because reads of buf[(t-1)&3] retire before the end-of-iter-(t-1) barrier and
// stage(t+3) into that buffer issues after it.
enum { EPI_BF16 = 0, EPI_BF16_GELU = 1, EPI_F32_RESID = 2, EPI_F32 = 3 };

template <int EPI, int BM, int NWM>
__global__ __launch_bounds__(256) void gemm_p3_kernel(
    const u16* __restrict__ A, const u16* __restrict__ B,
    const float* __restrict__ bias, const float* resid, void* out,
    int N, int K, int mtiles, int nwg8)
{
    constexpr int NWN = 4 / NWM;
    constexpr int MI  = (BM / NWM) / 16;
    constexpr int NI  = (128 / NWN) / 16;
    constexpr int ASHOTS = (BM * 4) / 256;   // A-tile 16B chunks per thread
    constexpr int LPS = ASHOTS + 2;          // loads per stage per thread
    __shared__ u16 As[4][BM][32];
    __shared__ u16 Bs[4][128][32];
    int tid = threadIdx.x;
    int l = tid & 63, w = tid >> 6;
    int lw = l & 15, lg = l >> 4;
    int bid = blockIdx.x;
    int wg = (bid & 7) * nwg8 + (bid >> 3);   // bijective XCD swizzle (nwg%8==0)
    int mt = wg % mtiles, nt = wg / mtiles;
    int row0 = mt * BM, col0 = nt * 128;
    int wm = w % NWM, wn = w / NWM;
    int mbase = wm * (BM / NWM), nbase = wn * (128 / NWN);

    f32x4 acc[MI][NI] = {};
    const int ntiles = K >> 5;

    auto stage = [&](int nb, int kk) {
        u16* asb = &As[nb][0][0];
        u16* bsb = &Bs[nb][0][0];
#pragma unroll
        for (int s = 0; s < ASHOTS; s++) {
            int c = s * 256 + tid;
            int r = c >> 2, q = (c & 3) * 8;
            gload16(A + (size_t)(row0 + r) * K + kk + q, asb + r * 32 + q);
        }
#pragma unroll
        for (int s = 0; s < 2; s++) {
            int c = s * 256 + tid;
            int r = c >> 2, q = (c & 3) * 8;
            gload16(B + (size_t)(col0 + r) * K + kk + q, bsb + r * 32 + q);
        }
    };

    // prologue: fill 3 stages, wait for the oldest, sync
    stage(0, 0);
    stage(1, 32);
    stage(2, 64);
    wait_vmcnt<2 * LPS>();
    __builtin_amdgcn_s_barrier();

    for (int t = 0; t < ntiles; ++t) {
        int cur = t & 3;
        bf16x8 af[MI], bfr[NI];
#pragma unroll
        for (int mi = 0; mi < MI; mi++)
            af[mi] = *reinterpret_cast<const bf16x8*>(&As[cur][mbase + mi * 16 + lw][lg * 8]);
#pragma unroll
        for (int ni = 0; ni < NI; ni++)
            bfr[ni] = *reinterpret_cast<const bf16x8*>(&Bs[cur][nbase + ni * 16 + lw][lg * 8]);
        if (t + 3 < ntiles) stage((t + 3) & 3, (t + 3) << 5);
        __builtin_amdgcn_s_setprio(1);
#pragma unroll
        for (int mi = 0; mi < MI; mi++)
#pragma unroll
            for (int ni = 0; ni < NI; ni++)
                acc[mi][ni] = __builtin_amdgcn_mfma_f32_16x16x32_bf16(af[mi], bfr[ni], acc[mi][ni], 0, 0, 0);
        __builtin_amdgcn_s_setprio(0);
        int rem = ntiles - 1 - t;            // stages that must still land after this iter
        if (rem >= 3)      wait_vmcnt<2 * LPS>();
        else if (rem == 2) wait_vmcnt<LPS>();
        else if (rem == 1) wait_vmcnt<0>();
        __builtin_amdgcn_s_barrier();
    }

#pragma unroll
    for (int mi = 0; mi < MI; mi++) {
#pragma unroll
        for (int ni = 0; ni < NI; ni++) {
            int colc = col0 + nbase + ni * 16 + lw;
            float bv = bias ? bias[colc] : 0.0f;
#pragma unroll
            for (int j = 0; j < 4; j++) {
                int row = row0 + mbase + mi * 16 + lg * 4 + j;
                size_t off = (size_t)row * N + colc;
                float v = acc[mi][ni][j] + bv;
                if constexpr (EPI == EPI_BF16) {
                    ((u16*)out)[off] = f2bf(v);
                } else if constexpr (EPI == EPI_BF16_GELU) {
                    ((u16*)out)[off] = f2bf(gelu_f(v));
                } else if constexpr (EPI == EPI_F32_RESID) {
                    ((float*)out)[off] = v + resid[off];
                } else {
                    ((float*)out)[off] = v;
                }
            }
        }
    }
}

// ---------------------------------------------------------------- GEMM fallback (fp32 weights)
template <int EPI>
__global__ __launch_bounds__(256) void gemm_kernel(
    const u16* __restrict__ A, const float* __restrict__ Bw,
    const float* __restrict__ bias, const float* resid, void* out,
    int N, int K)
{
    constexpr int M = 2048;
    __shared__ u16 As[128][40];
    __shared__ u16 Bs[128][40];
    int tid = threadIdx.x;
    int l = tid & 63, w = tid >> 6;
    int lw = l & 15, lg = l >> 4;
    int mtiles = M / 128;
    int mt = blockIdx.x % mtiles, nt = blockIdx.x / mtiles;
    int row0 = mt * 128, col0 = nt * 128;
    int mbase = (w & 1) * 64, nbase = (w >> 1) * 64;
    f32x4 acc[4][4] = {};

    for (int kk = 0; kk < K; kk += 32) {
        int c = tid;
#pragma unroll
        for (int i = 0; i < 2; i++, c += 256) {
            int r = c >> 2, q = c & 3;
            uint4 u = *reinterpret_cast<const uint4*>(A + (size_t)(row0 + r) * K + kk + q * 8);
            *reinterpret_cast<uint4*>(&As[r][q * 8]) = u;
        }
        int c2 = tid;
#pragma unroll
        for (int i = 0; i < 4; i++, c2 += 256) {
            int r = c2 >> 3, q = c2 & 7;
            const float4 f = *reinterpret_cast<const float4*>(Bw + (size_t)(col0 + r) * K + kk + q * 4);
            union { u16 h[4]; uint2 u; } cv;
            cv.h[0] = f2bf(f.x); cv.h[1] = f2bf(f.y); cv.h[2] = f2bf(f.z); cv.h[3] = f2bf(f.w);
            *reinterpret_cast<uint2*>(&Bs[r][q * 4]) = cv.u;
        }
        __syncthreads();
        bf16x8 af[4], bfr[4];
#pragma unroll
        for (int mi = 0; mi < 4; mi++)
            af[mi] = *reinterpret_cast<const bf16x8*>(&As[mbase + mi * 16 + lw][lg * 8]);
#pragma unroll
        for (int ni = 0; ni < 4; ni++)
            bfr[ni] = *reinterpret_cast<const bf16x8*>(&Bs[nbase + ni * 16 + lw][lg * 8]);
#pragma unroll
        for (int mi = 0; mi < 4; mi++)
#pragma unroll
            for (int ni = 0; ni < 4; ni++)
                acc[mi][ni] = __builtin_amdgcn_mfma_f32_16x16x32_bf16(af[mi], bfr[ni], acc[mi][ni], 0, 0, 0);
        __syncthreads();
    }

#pragma unroll
    for (int mi = 0; mi < 4; mi++) {
#pragma unroll
        for (int ni = 0; ni < 4; ni++) {
            int colc = col0 + nbase + ni * 16 + lw;
            float bv = bias ? bias[colc] : 0.0f;
#pragma unroll
            for (int j = 0; j < 4; j++) {
                int row = row0 + mbase + mi * 16 + lg * 4 + j;
                size_t off = (size_t)row * N + colc;
                float v = acc[mi][ni][j] + bv;
                if constexpr (EPI == EPI_BF16) {
                    ((u16*)out)[off] = f2bf(v);
                } else if constexpr (EPI == EPI_BF16_GELU) {
                    ((u16*)out)[off] = f2bf(gelu_f(v));
                } else if constexpr (EPI == EPI_F32_RESID) {
                    ((float*)out)[off] = v + resid[off];
                } else {
                    ((float*)out)[off] = v;
                }
            }
        }
    }
}

// ---------------------------------------------------------------- attention
__global__ __launch_bounds__(256) void attn_kernel(
    const u16* __restrict__ qkv, const int* __restrict__ idx, u16* __restrict__ yv)
{
    __shared__ u16 Kt[32][72];
    __shared__ u16 Vt[64][40];
    __shared__ u16 Pb[4][16][40];
    __shared__ int kval[32];

    int tid = threadIdx.x, l = tid & 63, w = tid >> 6;
    int lw = l & 15, lg = l >> 4;
    int bid = blockIdx.x;
    int qb = bid & 15;
    int h = (bid >> 4) % 12;
    int b = bid / (16 * 12);
    const size_t base = (size_t)b * 1024;

    int qrow = qb * 64 + w * 16 + lw;
    const u16* qp = qkv + (base + qrow) * 2304 + h * 64;
    bf16x8 aq0 = *reinterpret_cast<const bf16x8*>(qp + lg * 8);
    bf16x8 aq1 = *reinterpret_cast<const bf16x8*>(qp + 32 + lg * 8);

    int rowj[4], vq[4];
#pragma unroll
    for (int j = 0; j < 4; j++) {
        rowj[j] = qb * 64 + w * 16 + lg * 4 + j;
        vq[j] = idx[base + rowj[j]] > 0;
    }
    float m[4], lsum[4];
    f32x4 O[4] = {};
#pragma unroll
    for (int j = 0; j < 4; j++) { m[j] = -__builtin_inff(); lsum[j] = 0.0f; }

    int kvend = qb * 64 + 64;
    for (int kv0 = 0; kv0 < kvend; kv0 += 32) {
        {
            int r = tid >> 3, cc = tid & 7;
            const u16* kp = qkv + (base + kv0 + r) * 2304 + 768 + h * 64 + cc * 8;
            uint4 ku = *reinterpret_cast<const uint4*>(kp);
            *reinterpret_cast<uint4*>(&Kt[r][cc * 8]) = ku;
            const u16* vp = qkv + (base + kv0 + r) * 2304 + 1536 + h * 64 + cc * 8;
            union { uint4 u; u16 h8[8]; } vu;
            vu.u = *reinterpret_cast<const uint4*>(vp);
#pragma unroll
            for (int j2 = 0; j2 < 8; j2++) Vt[cc * 8 + j2][r] = vu.h8[j2];
            if (tid < 32) kval[tid] = idx[base + kv0 + tid] > 0;
        }
        __syncthreads();

        f32x4 S[2];
#pragma unroll
        for (int g = 0; g < 2; g++) {
            bf16x8 bk0 = *reinterpret_cast<const bf16x8*>(&Kt[g * 16 + lw][lg * 8]);
            bf16x8 bk1 = *reinterpret_cast<const bf16x8*>(&Kt[g * 16 + lw][32 + lg * 8]);
            f32x4 t = {};
            t = __builtin_amdgcn_mfma_f32_16x16x32_bf16(aq0, bk0, t, 0, 0, 0);
            t = __builtin_amdgcn_mfma_f32_16x16x32_bf16(aq1, bk1, t, 0, 0, 0);
            S[g] = t;
        }
        float p[2][4];
#pragma unroll
        for (int j = 0; j < 4; j++) {
            float sv0, sv1;
#pragma unroll
            for (int g = 0; g < 2; g++) {
                int kcol = kv0 + g * 16 + lw;
                float s = S[g][j] * 0.125f;
                bool keep = (kcol <= rowj[j]) &&
                            ((vq[j] && kval[g * 16 + lw]) || (kcol == rowj[j]));
                s = keep ? s : -__builtin_inff();
                if (g) sv1 = s; else sv0 = s;
            }
            float mx = fmaxf(sv0, sv1);
            mx = fmaxf(mx, __shfl_xor(mx, 1));
            mx = fmaxf(mx, __shfl_xor(mx, 2));
            mx = fmaxf(mx, __shfl_xor(mx, 4));
            mx = fmaxf(mx, __shfl_xor(mx, 8));
            float mn = fmaxf(m[j], mx);
            float mclamp = fmaxf(mn, -1e30f);
            float scale = __expf(m[j] - mclamp);
            float p0 = __expf(sv0 - mclamp);
            float p1 = __expf(sv1 - mclamp);
            float rs = p0 + p1;
            rs += __shfl_xor(rs, 1); rs += __shfl_xor(rs, 2);
            rs += __shfl_xor(rs, 4); rs += __shfl_xor(rs, 8);
            lsum[j] = lsum[j] * scale + rs;
            m[j] = mn;
#pragma unroll
            for (int ni = 0; ni < 4; ni++) O[ni][j] *= scale;
            p[0][j] = p0; p[1][j] = p1;
        }
#pragma unroll
        for (int g = 0; g < 2; g++)
#pragma unroll
            for (int j = 0; j < 4; j++)
                Pb[w][lg * 4 + j][g * 16 + lw] = f2bf(p[g][j]);
        bf16x8 ap = *reinterpret_cast<const bf16x8*>(&Pb[w][lw][lg * 8]);
#pragma unroll
        for (int ni = 0; ni < 4; ni++) {
            bf16x8 bv = *reinterpret_cast<const bf16x8*>(&Vt[ni * 16 + lw][lg * 8]);
            O[ni] = __builtin_amdgcn_mfma_f32_16x16x32_bf16(ap, bv, O[ni], 0, 0, 0);
        }
        __syncthreads();
    }

#pragma unroll
    for (int j = 0; j < 4; j++) {
        float inv = 1.0f / lsum[j];
#pragma unroll
        for (int ni = 0; ni < 4; ni++) {
            float v = O[ni][j] * inv;
            yv[(base + rowj[j]) * 768 + h * 64 + ni * 16 + lw] = f2bf(v);
        }
    }
}

// ---------------------------------------------------------------- host
// BM=64 for N=768 (more workgroups on 256 CUs), BM=128 otherwise.
static void launch_gemm_db(int epi, const u16* A, const u16* B, const float* bias,
                           const float* resid, void* out, int N, int K, hipStream_t s)
{
    dim3 blk(256);
    if (N == 768) {
        constexpr int BM = 64, NWM = 1;
        int mtiles = 2048 / BM;
        int nwg = mtiles * (N / 128);
        dim3 grid(nwg);
        int nwg8 = nwg / 8;
        switch (epi) {
            case EPI_BF16:      gemm_p3_kernel<EPI_BF16, BM, NWM><<<grid, blk, 0, s>>>(A, B, bias, resid, out, N, K, mtiles, nwg8); break;
            case EPI_BF16_GELU: gemm_p3_kernel<EPI_BF16_GELU, BM, NWM><<<grid, blk, 0, s>>>(A, B, bias, resid, out, N, K, mtiles, nwg8); break;
            case EPI_F32_RESID: gemm_p3_kernel<EPI_F32_RESID, BM, NWM><<<grid, blk, 0, s>>>(A, B, bias, resid, out, N, K, mtiles, nwg8); break;
            default:            gemm_p3_kernel<EPI_F32, BM, NWM><<<grid, blk, 0, s>>>(A, B, bias, resid, out, N, K, mtiles, nwg8); break;
        }
    } else {
        constexpr int BM = 128, NWM = 2;
        int mtiles = 2048 / BM;
        int nwg = mtiles * (N / 128);
        dim3 grid(nwg);
        int nwg8 = nwg / 8;
        switch (epi) {
            case EPI_BF16:      gemm_p3_kernel<EPI_BF16, BM, NWM><<<grid, blk, 0, s>>>(A, B, bias, resid, out, N, K, mtiles, nwg8); break;
            case EPI_BF16_GELU: gemm_p3_kernel<EPI_BF16_GELU, BM, NWM><<<grid, blk, 0, s>>>(A, B, bias, resid, out, N, K, mtiles, nwg8); break;
            case EPI_F32_RESID: gemm_p3_kernel<EPI_F32_RESID, BM, NWM><<<grid, blk, 0, s>>>(A, B, bias, resid, out, N, K, mtiles, nwg8); break;
            default:            gemm_p3_kernel<EPI_F32, BM, NWM><<<grid, blk, 0, s>>>(A, B, bias, resid, out, N, K, mtiles, nwg8); break;
        }
    }
}

static void launch_gemm_f32w(int epi, const u16* A, const float* Bw, const float* bias,
                             const float* resid, void* out, int N, int K, hipStream_t s)
{
    dim3 grid((2048 / 128) * (N / 128)), blk(256);
    switch (epi) {
        case EPI_BF16:      gemm_kernel<EPI_BF16><<<grid, blk, 0, s>>>(A, Bw, bias, resid, out, N, K); break;
        case EPI_BF16_GELU: gemm_kernel<EPI_BF16_GELU><<<grid, blk, 0, s>>>(A, Bw, bias, resid, out, N, K); break;
        case EPI_F32_RESID: gemm_kernel<EPI_F32_RESID><<<grid, blk, 0, s>>>(A, Bw, bias, resid, out, N, K); break;
        default:            gemm_kernel<EPI_F32><<<grid, blk, 0, s>>>(A, Bw, bias, resid, out, N, K); break;
    }
}

static void cvt(const float* src, u16* dst, size_t n, hipStream_t s) {
    int n4 = (int)(n / 4);
    int blocks = (n4 + 255) / 256;
    if (blocks > 2048) blocks = 2048;
    cvt_kernel<<<blocks, 256, 0, s>>>(src, dst, n4);
}

extern "C" void kernel_launch(void* const* d_in, const int* in_sizes, int n_in,
                              void* d_out, int out_size, void* d_ws, size_t ws_size,
                              hipStream_t stream)
{
    (void)in_sizes; (void)n_in; (void)out_size;
    const int*   idx    = (const int*)  d_in[0];
    const float* age    = (const float*)d_in[1];
    const float* wte    = (const float*)d_in[2];
    const float* wae_w  = (const float*)d_in[3];
    const float* ln1_w  = (const float*)d_in[4];
    const float* ln1_b  = (const float*)d_in[5];
    const float* attn_w = (const float*)d_in[6];
    const float* attn_b = (const float*)d_in[7];
    const float* proj_w = (const float*)d_in[8];
    const float* proj_b = (const float*)d_in[9];
    const float* ln2_w  = (const float*)d_in[10];
    const float* ln2_b  = (const float*)d_in[11];
    const float* fc_w   = (const float*)d_in[12];
    const float* fc_b   = (const float*)d_in[13];
    const float* fc2_w  = (const float*)d_in[14];
    const float* fc2_b  = (const float*)d_in[15];
    const float* lnf_w  = (const float*)d_in[16];
    const float* lnf_b  = (const float*)d_in[17];

    char* ws = (char*)d_ws;
    size_t off = 0;
    float* x   = (float*)(ws + off); off += (size_t)2048 * 768 * 4;
    u16* hb    = (u16*)(ws + off);   off += (size_t)2048 * 768 * 2;
    u16* qkvb  = (u16*)(ws + off);   off += (size_t)2048 * 2304 * 2;
    u16* yvb   = (u16*)(ws + off);   off += (size_t)2048 * 768 * 2;
    u16* a1b   = (u16*)(ws + off);   off += (size_t)2048 * 3072 * 2;
    u16* yage  = (u16*)(ws + off);   off += (size_t)2048 * 768 * 2;
    // bf16 weight mirrors
    u16* wte_b  = (u16*)(ws + off);  off += (size_t)32768 * 768 * 2;
    u16* attn_wb= (u16*)(ws + off);  off += (size_t)4 * 2304 * 768 * 2;
    u16* proj_wb= (u16*)(ws + off);  off += (size_t)4 * 768 * 768 * 2;
    u16* fc_wb  = (u16*)(ws + off);  off += (size_t)4 * 3072 * 768 * 2;
    u16* fc2_wb = (u16*)(ws + off);  off += (size_t)4 * 768 * 3072 * 2;
    u16* wae_wb = (u16*)(ws + off);  off += (size_t)768 * 768 * 2;
    const size_t NEED = off;

    if (ws_size >= NEED) {
        cvt(wte,    wte_b,   (size_t)32768 * 768, stream);
        cvt(attn_w, attn_wb, (size_t)4 * 2304 * 768, stream);
        cvt(proj_w, proj_wb, (size_t)4 * 768 * 768, stream);
        cvt(fc_w,   fc_wb,   (size_t)4 * 3072 * 768, stream);
        cvt(fc2_w,  fc2_wb,  (size_t)4 * 768 * 3072, stream);
        cvt(wae_w,  wae_wb,  (size_t)768 * 768, stream);

        embed_kernel<<<2048, 256, 0, stream>>>(idx, age, wte, x, yage);
        launch_gemm_db(EPI_F32_RESID, yage, wae_wb, nullptr, x, x, 768, 768, stream);

        for (int li = 0; li < 4; li++) {
            ln_kernel<<<2048, 256, 0, stream>>>(x, ln1_w + li * 768, ln1_b + li * 768, hb);
            launch_gemm_db(EPI_BF16, hb, attn_wb + (size_t)li * 2304 * 768, attn_b + li * 2304,
                           nullptr, qkvb, 2304, 768, stream);
            attn_kernel<<<2 * 12 * 16, 256, 0, stream>>>(qkvb, idx, yvb);
            launch_gemm_db(EPI_F32_RESID, yvb, proj_wb + (size_t)li * 768 * 768, proj_b + li * 768,
                           x, x, 768, 768, stream);
            ln_kernel<<<2048, 256, 0, stream>>>(x, ln2_w + li * 768, ln2_b + li * 768, hb);
            launch_gemm_db(EPI_BF16_GELU, hb, fc_wb + (size_t)li * 3072 * 768, fc_b + li * 3072,
                           nullptr, a1b, 3072, 768, stream);
            launch_gemm_db(EPI_F32_RESID, a1b, fc2_wb + (size_t)li * 768 * 3072, fc2_b + li * 768,
                           x, x, 768, 3072, stream);
        }

        ln_kernel<<<2048, 256, 0, stream>>>(x, lnf_w, lnf_b, hb);
        launch_gemm_db(EPI_F32, hb, wte_b, nullptr, nullptr, d_out, 32768, 768, stream);
    } else {
        // fallback: fp32-weight path
        embed_kernel<<<2048, 256, 0, stream>>>(idx, age, wte, x, yage);
        launch_gemm_f32w(EPI_F32_RESID, yage, wae_w, nullptr, x, x, 768, 768, stream);
        for (int li = 0; li < 4; li++) {
            ln_kernel<<<2048, 256, 0, stream>>>(x, ln1_w + li * 768, ln1_b + li * 768, hb);
            launch_gemm_f32w(EPI_BF16, hb, attn_w + (size_t)li * 2304 * 768, attn_b + li * 2304,
                             nullptr, qkvb, 2304, 768, stream);
            attn_kernel<<<2 * 12 * 16, 256, 0, stream>>>(qkvb, idx, yvb);
            launch_gemm_f32w(EPI_F32_RESID, yvb, proj_w + (size_t)li * 768 * 768, proj_b + li * 768,
                             x, x, 768, 768, stream);
            ln_kernel<<<2048, 256, 0, stream>>>(x, ln2_w + li * 768, ln2_b + li * 768, hb);
            launch_gemm_f32w(EPI_BF16_GELU, hb, fc_w + (size_t)li * 3072 * 768, fc_b + li * 3072,
                             nullptr, a1b, 3072, 768, stream);
            launch_gemm_f32w(EPI_F32_RESID, a1b, fc2_w + (size_t)li * 768 * 3072, fc2_b + li * 768,
                             x, x, 768, 3072, stream);
        }
        ln_kernel<<<2048, 256, 0, stream>>>(x, lnf_w, lnf_b, hb);
        launch_gemm_f32w(EPI_F32, hb, wte, nullptr, nullptr, d_out, 32768, 768, stream);
    }
}

// Round 8
// 1476.423 us; speedup vs baseline: 1.3958x; 1.0513x over previous
//
#include <hip/hip_runtime.h>

typedef unsigned short u16;
typedef __bf16 bf16x8 __attribute__((ext_vector_type(8)));
typedef float f32x4 __attribute__((ext_vector_type(4)));

// fp32 -> bf16 round-to-nearest-even
__device__ __forceinline__ u16 f2bf(float f) {
    union { float f; unsigned int u; } c; c.f = f;
    unsigned int u = c.u;
    unsigned int r = (u + 0x7FFFu + ((u >> 16) & 1u)) >> 16;
    return (u16)r;
}

__device__ __forceinline__ float gelu_f(float v) {
    const float c = 0.7978845608028654f;
    float t = tanhf(c * (v + 0.044715f * v * v * v));
    return 0.5f * v * (1.0f + t);
}

typedef const __attribute__((address_space(1))) unsigned int* as1_u32p;
typedef __attribute__((address_space(3))) unsigned int* as3_u32p;
typedef const __attribute__((address_space(3))) u16* as3_cu16p;
__device__ __forceinline__ void gload16(const void* g, void* l) {
    __builtin_amdgcn_global_load_lds((as1_u32p)g, (as3_u32p)l, 16, 0, 0);
}

// LDS read the compiler can't tie to the global_load_lds vmcnt state.
// MUST be followed (after the cluster) by s_waitcnt lgkmcnt(0) + sched_barrier(0).
__device__ __forceinline__ bf16x8 ds_read_frag(const u16* p) {
    bf16x8 r;
    as3_cu16p lp = (as3_cu16p)p;
    asm volatile("ds_read_b128 %0, %1" : "=v"(r) : "v"(lp));
    return r;
}

template <int N> __device__ __forceinline__ void wait_vmcnt() {
    if constexpr (N == 0)      asm volatile("s_waitcnt vmcnt(0)" ::: "memory");
    else if constexpr (N == 3) asm volatile("s_waitcnt vmcnt(3)" ::: "memory");
    else if constexpr (N == 4) asm volatile("s_waitcnt vmcnt(4)" ::: "memory");
    else if constexpr (N == 6) asm volatile("s_waitcnt vmcnt(6)" ::: "memory");
    else if constexpr (N == 8) asm volatile("s_waitcnt vmcnt(8)" ::: "memory");
}

// ---------------------------------------------------------------- weight convert
__global__ __launch_bounds__(256) void cvt_kernel(
    const float* __restrict__ src, u16* __restrict__ dst, int n4)
{
    int i = blockIdx.x * 256 + threadIdx.x;
    int stride = gridDim.x * 256;
    for (; i < n4; i += stride) {
        float4 f = reinterpret_cast<const float4*>(src)[i];
        union { u16 h[4]; uint2 u; } cv;
        cv.h[0] = f2bf(f.x); cv.h[1] = f2bf(f.y);
        cv.h[2] = f2bf(f.z); cv.h[3] = f2bf(f.w);
        reinterpret_cast<uint2*>(dst)[i] = cv.u;
    }
}

// ---------------------------------------------------------------- embedding
__global__ __launch_bounds__(256) void embed_kernel(
    const int* __restrict__ idx, const float* __restrict__ age,
    const float* __restrict__ wte, float* __restrict__ x, u16* __restrict__ y)
{
    int t = blockIdx.x;
    int tid = threadIdx.x;
    int tok = idx[t];
    float a = age[t] * (1.0f / 365.25f);
    const float kc = -9.210340371976184f / 768.0f;   // -ln(10000)/D
#pragma unroll
    for (int j = 0; j < 3; j++) {
        int d = tid + j * 256;
        x[(size_t)t * 768 + d] = wte[(size_t)tok * 768 + d];
        int twoi = d & ~1;
        float dv = __expf(kc * (float)twoi);
        float ang = a * dv;
        float val = (d & 1) ? __cosf(ang) : __sinf(ang);
        y[(size_t)t * 768 + d] = f2bf(val);
    }
}

// ---------------------------------------------------------------- layernorm
__global__ __launch_bounds__(256) void ln_kernel(
    const float* __restrict__ x, const float* __restrict__ w,
    const float* __restrict__ b, u16* __restrict__ out)
{
    int row = blockIdx.x;
    int tid = threadIdx.x;
    int l = tid & 63, wv = tid >> 6;
    const float* xr = x + (size_t)row * 768;
    float v[3], s = 0.f, ss = 0.f;
#pragma unroll
    for (int j = 0; j < 3; j++) { v[j] = xr[tid + j * 256]; s += v[j]; ss += v[j] * v[j]; }
#pragma unroll
    for (int d = 1; d < 64; d <<= 1) { s += __shfl_xor(s, d); ss += __shfl_xor(ss, d); }
    __shared__ float ps[4], pss[4];
    if (l == 0) { ps[wv] = s; pss[wv] = ss; }
    __syncthreads();
    s = ps[0] + ps[1] + ps[2] + ps[3];
    ss = pss[0] + pss[1] + pss[2] + pss[3];
    float mu = s * (1.0f / 768.0f);
    float var = ss * (1.0f / 768.0f) - mu * mu;
    float rstd = rsqrtf(var + 1e-5f);
#pragma unroll
    for (int j = 0; j < 3; j++) {
        int d = tid + j * 256;
        out[(size_t)row * 768 + d] = f2bf((v[j] - mu) * rstd * w[d] + b[d]);
    }
}

// ---------------------------------------------------------------- GEMM (3-buffer depth-2 counted-vmcnt pipeline)
// C[M=2048,N] = A[M,K](bf16) @ B[N,K](bf16)^T + bias ; XCD-swizzled grid, mt fastest.
// Fragment loads via inline-asm ds_read_b128 (compiler can't see the LDS<-gload
// dependency, so it emits NO vmcnt before them); correctness from our explicit
// counted vmcnt + raw barrier. stage(t+2) targets buf[(t-1)%3], whose reads all
// retired before the end-of-iter-(t-1) barrier (WAR safe). Per-wave vmcnt + barrier
// => stage(t) landed block-wide before iter t reads it (RAW safe).
enum { EPI_BF16 = 0, EPI_BF16_GELU = 1, EPI_F32_RESID = 2, EPI_F32 = 3 };

template <int EPI, int BM, int NWM>
__global__ __launch_bounds__(256) void gemm_p2_kernel(
    const u16* __restrict__ A, const u16* __restrict__ B,
    const float* __restrict__ bias, const float* resid, void* out,
    int N, int K, int mtiles, int nwg8)
{
    constexpr int NWN = 4 / NWM;
    constexpr int MI  = (BM / NWM) / 16;
    constexpr int NI  = (128 / NWN) / 16;
    constexpr int ASHOTS = (BM * 4) / 256;   // A-tile 16B chunks per thread
    constexpr int LPS = ASHOTS + 2;          // loads per stage per thread
    __shared__ u16 As[3][BM][32];
    __shared__ u16 Bs[3][128][32];
    int tid = threadIdx.x;
    int l = tid & 63, w = tid >> 6;
    int lw = l & 15, lg = l >> 4;
    int bid = blockIdx.x;
    int wg = (bid & 7) * nwg8 + (bid >> 3);   // bijective XCD swizzle (nwg%8==0)
    int mt = wg % mtiles, nt = wg / mtiles;
    int row0 = mt * BM, col0 = nt * 128;
    int wm = w % NWM, wn = w / NWM;
    int mbase = wm * (BM / NWM), nbase = wn * (128 / NWN);

    // staging pointers: lane-linear (matches global_load_lds base+lane*16 semantics)
    const u16* ga = A + (size_t)(row0 + (tid >> 2)) * K + (tid & 3) * 8;
    const u16* gb = B + (size_t)(col0 + (tid >> 2)) * K + (tid & 3) * 8;
    const size_t k64 = (size_t)64 * K;
    int dofs = tid * 8;                       // element offset within a stage buffer

    f32x4 acc[MI][NI] = {};
    const int ntiles = K >> 5;

    auto stage = [&](int nb, int kk) {
        u16* asb = &As[nb][0][0];
        u16* bsb = &Bs[nb][0][0];
#pragma unroll
        for (int s = 0; s < ASHOTS; s++)
            gload16(ga + s * k64 + kk, asb + s * 2048 + dofs);
#pragma unroll
        for (int s = 0; s < 2; s++)
            gload16(gb + s * k64 + kk, bsb + s * 2048 + dofs);
    };

    // prologue: fill 2 stages, wait for the oldest, sync
    stage(0, 0);
    stage(1, 32);
    wait_vmcnt<LPS>();
    __builtin_amdgcn_s_barrier();

    int cur = 0;
    for (int t = 0; t < ntiles; ++t) {
        int prv = cur == 0 ? 2 : cur - 1;     // == (t+2)%3
        if (t + 2 < ntiles) stage(prv, (t + 2) << 5);
        bf16x8 af[MI], bfr[NI];
#pragma unroll
        for (int mi = 0; mi < MI; mi++)
            af[mi] = ds_read_frag(&As[cur][mbase + mi * 16 + lw][lg * 8]);
#pragma unroll
        for (int ni = 0; ni < NI; ni++)
            bfr[ni] = ds_read_frag(&Bs[cur][nbase + ni * 16 + lw][lg * 8]);
        asm volatile("s_waitcnt lgkmcnt(0)" ::: "memory");
        __builtin_amdgcn_sched_barrier(0);
        __builtin_amdgcn_s_setprio(1);
#pragma unroll
        for (int mi = 0; mi < MI; mi++)
#pragma unroll
            for (int ni = 0; ni < NI; ni++)
                acc[mi][ni] = __builtin_amdgcn_mfma_f32_16x16x32_bf16(af[mi], bfr[ni], acc[mi][ni], 0, 0, 0);
        __builtin_amdgcn_s_setprio(0);
        if (t + 2 < ntiles)      wait_vmcnt<LPS>();   // stage t+1 landed; t+2 still flying
        else if (t + 1 < ntiles) wait_vmcnt<0>();     // tail: drain last stage
        __builtin_amdgcn_s_barrier();
        cur = cur == 2 ? 0 : cur + 1;
    }

#pragma unroll
    for (int mi = 0; mi < MI; mi++) {
#pragma unroll
        for (int ni = 0; ni < NI; ni++) {
            int colc = col0 + nbase + ni * 16 + lw;
            float bv = bias ? bias[colc] : 0.0f;
#pragma unroll
            for (int j = 0; j < 4; j++) {
                int row = row0 + mbase + mi * 16 + lg * 4 + j;
                size_t off = (size_t)row * N + colc;
                float v = acc[mi][ni][j] + bv;
                if constexpr (EPI == EPI_BF16) {
                    ((u16*)out)[off] = f2bf(v);
                } else if constexpr (EPI == EPI_BF16_GELU) {
                    ((u16*)out)[off] = f2bf(gelu_f(v));
                } else if constexpr (EPI == EPI_F32_RESID) {
                    ((float*)out)[off] = v + resid[off];
                } else {
                    ((float*)out)[off] = v;
                }
            }
        }
    }
}

// ---------------------------------------------------------------- GEMM fallback (fp32 weights)
template <int EPI>
__global__ __launch_bounds__(256) void gemm_kernel(
    const u16* __restrict__ A, const float* __restrict__ Bw,
    const float* __restrict__ bias, const float* resid, void* out,
    int N, int K)
{
    constexpr int M = 2048;
    __shared__ u16 As[128][40];
    __shared__ u16 Bs[128][40];
    int tid = threadIdx.x;
    int l = tid & 63, w = tid >> 6;
    int lw = l & 15, lg = l >> 4;
    int mtiles = M / 128;
    int mt = blockIdx.x % mtiles, nt = blockIdx.x / mtiles;
    int row0 = mt * 128, col0 = nt * 128;
    int mbase = (w & 1) * 64, nbase = (w >> 1) * 64;
    f32x4 acc[4][4] = {};

    for (int kk = 0; kk < K; kk += 32) {
        int c = tid;
#pragma unroll
        for (int i = 0; i < 2; i++, c += 256) {
            int r = c >> 2, q = c & 3;
            uint4 u = *reinterpret_cast<const uint4*>(A + (size_t)(row0 + r) * K + kk + q * 8);
            *reinterpret_cast<uint4*>(&As[r][q * 8]) = u;
        }
        int c2 = tid;
#pragma unroll
        for (int i = 0; i < 4; i++, c2 += 256) {
            int r = c2 >> 3, q = c2 & 7;
            const float4 f = *reinterpret_cast<const float4*>(Bw + (size_t)(col0 + r) * K + kk + q * 4);
            union { u16 h[4]; uint2 u; } cv;
            cv.h[0] = f2bf(f.x); cv.h[1] = f2bf(f.y); cv.h[2] = f2bf(f.z); cv.h[3] = f2bf(f.w);
            *reinterpret_cast<uint2*>(&Bs[r][q * 4]) = cv.u;
        }
        __syncthreads();
        bf16x8 af[4], bfr[4];
#pragma unroll
        for (int mi = 0; mi < 4; mi++)
            af[mi] = *reinterpret_cast<const bf16x8*>(&As[mbase + mi * 16 + lw][lg * 8]);
#pragma unroll
        for (int ni = 0; ni < 4; ni++)
            bfr[ni] = *reinterpret_cast<const bf16x8*>(&Bs[nbase + ni * 16 + lw][lg * 8]);
#pragma unroll
        for (int mi = 0; mi < 4; mi++)
#pragma unroll
            for (int ni = 0; ni < 4; ni++)
                acc[mi][ni] = __builtin_amdgcn_mfma_f32_16x16x32_bf16(af[mi], bfr[ni], acc[mi][ni], 0, 0, 0);
        __syncthreads();
    }

#pragma unroll
    for (int mi = 0; mi < 4; mi++) {
#pragma unroll
        for (int ni = 0; ni < 4; ni++) {
            int colc = col0 + nbase + ni * 16 + lw;
            float bv = bias ? bias[colc] : 0.0f;
#pragma unroll
            for (int j = 0; j < 4; j++) {
                int row = row0 + mbase + mi * 16 + lg * 4 + j;
                size_t off = (size_t)row * N + colc;
                float v = acc[mi][ni][j] + bv;
                if constexpr (EPI == EPI_BF16) {
                    ((u16*)out)[off] = f2bf(v);
                } else if constexpr (EPI == EPI_BF16_GELU) {
                    ((u16*)out)[off] = f2bf(gelu_f(v));
                } else if constexpr (EPI == EPI_F32_RESID) {
                    ((float*)out)[off] = v + resid[off];
                } else {
                    ((float*)out)[off] = v;
                }
            }
        }
    }
}

// ---------------------------------------------------------------- attention
__global__ __launch_bounds__(256) void attn_kernel(
    const u16* __restrict__ qkv, const int* __restrict__ idx, u16* __restrict__ yv)
{
    __shared__ u16 Kt[32][72];
    __shared__ u16 Vt[64][40];
    __shared__ u16 Pb[4][16][40];
    __shared__ int kval[32];

    int tid = threadIdx.x, l = tid & 63, w = tid >> 6;
    int lw = l & 15, lg = l >> 4;
    int bid = blockIdx.x;
    int qb = bid & 15;
    int h = (bid >> 4) % 12;
    int b = bid / (16 * 12);
    const size_t base = (size_t)b * 1024;

    int qrow = qb * 64 + w * 16 + lw;
    const u16* qp = qkv + (base + qrow) * 2304 + h * 64;
    bf16x8 aq0 = *reinterpret_cast<const bf16x8*>(qp + lg * 8);
    bf16x8 aq1 = *reinterpret_cast<const bf16x8*>(qp + 32 + lg * 8);

    int rowj[4], vq[4];
#pragma unroll
    for (int j = 0; j < 4; j++) {
        rowj[j] = qb * 64 + w * 16 + lg * 4 + j;
        vq[j] = idx[base + rowj[j]] > 0;
    }
    float m[4], lsum[4];
    f32x4 O[4] = {};
#pragma unroll
    for (int j = 0; j < 4; j++) { m[j] = -__builtin_inff(); lsum[j] = 0.0f; }

    int kvend = qb * 64 + 64;
    for (int kv0 = 0; kv0 < kvend; kv0 += 32) {
        {
            int r = tid >> 3, cc = tid & 7;
            const u16* kp = qkv + (base + kv0 + r) * 2304 + 768 + h * 64 + cc * 8;
            uint4 ku = *reinterpret_cast<const uint4*>(kp);
            *reinterpret_cast<uint4*>(&Kt[r][cc * 8]) = ku;
            const u16* vp = qkv + (base + kv0 + r) * 2304 + 1536 + h * 64 + cc * 8;
            union { uint4 u; u16 h8[8]; } vu;
            vu.u = *reinterpret_cast<const uint4*>(vp);
#pragma unroll
            for (int j2 = 0; j2 < 8; j2++) Vt[cc * 8 + j2][r] = vu.h8[j2];
            if (tid < 32) kval[tid] = idx[base + kv0 + tid] > 0;
        }
        __syncthreads();

        f32x4 S[2];
#pragma unroll
        for (int g = 0; g < 2; g++) {
            bf16x8 bk0 = *reinterpret_cast<const bf16x8*>(&Kt[g * 16 + lw][lg * 8]);
            bf16x8 bk1 = *reinterpret_cast<const bf16x8*>(&Kt[g * 16 + lw][32 + lg * 8]);
            f32x4 t = {};
            t = __builtin_amdgcn_mfma_f32_16x16x32_bf16(aq0, bk0, t, 0, 0, 0);
            t = __builtin_amdgcn_mfma_f32_16x16x32_bf16(aq1, bk1, t, 0, 0, 0);
            S[g] = t;
        }
        float p[2][4];
#pragma unroll
        for (int j = 0; j < 4; j++) {
            float sv0, sv1;
#pragma unroll
            for (int g = 0; g < 2; g++) {
                int kcol = kv0 + g * 16 + lw;
                float s = S[g][j] * 0.125f;
                bool keep = (kcol <= rowj[j]) &&
                            ((vq[j] && kval[g * 16 + lw]) || (kcol == rowj[j]));
                s = keep ? s : -__builtin_inff();
                if (g) sv1 = s; else sv0 = s;
            }
            float mx = fmaxf(sv0, sv1);
            mx = fmaxf(mx, __shfl_xor(mx, 1));
            mx = fmaxf(mx, __shfl_xor(mx, 2));
            mx = fmaxf(mx, __shfl_xor(mx, 4));
            mx = fmaxf(mx, __shfl_xor(mx, 8));
            float mn = fmaxf(m[j], mx);
            float mclamp = fmaxf(mn, -1e30f);
            float scale = __expf(m[j] - mclamp);
            float p0 = __expf(sv0 - mclamp);
            float p1 = __expf(sv1 - mclamp);
            float rs = p0 + p1;
            rs += __shfl_xor(rs, 1); rs += __shfl_xor(rs, 2);
            rs += __shfl_xor(rs, 4); rs += __shfl_xor(rs, 8);
            lsum[j] = lsum[j] * scale + rs;
            m[j] = mn;
#pragma unroll
            for (int ni = 0; ni < 4; ni++) O[ni][j] *= scale;
            p[0][j] = p0; p[1][j] = p1;
        }
#pragma unroll
        for (int g = 0; g < 2; g++)
#pragma unroll
            for (int j = 0; j < 4; j++)
                Pb[w][lg * 4 + j][g * 16 + lw] = f2bf(p[g][j]);
        bf16x8 ap = *reinterpret_cast<const bf16x8*>(&Pb[w][lw][lg * 8]);
#pragma unroll
        for (int ni = 0; ni < 4; ni++) {
            bf16x8 bv = *reinterpret_cast<const bf16x8*>(&Vt[ni * 16 + lw][lg * 8]);
            O[ni] = __builtin_amdgcn_mfma_f32_16x16x32_bf16(ap, bv, O[ni], 0, 0, 0);
        }
        __syncthreads();
    }

#pragma unroll
    for (int j = 0; j < 4; j++) {
        float inv = 1.0f / lsum[j];
#pragma unroll
        for (int ni = 0; ni < 4; ni++) {
            float v = O[ni][j] * inv;
            yv[(base + rowj[j]) * 768 + h * 64 + ni * 16 + lw] = f2bf(v);
        }
    }
}

// ---------------------------------------------------------------- host
// BM=64 for N=768 (more workgroups on 256 CUs), BM=128 otherwise.
static void launch_gemm_db(int epi, const u16* A, const u16* B, const float* bias,
                           const float* resid, void* out, int N, int K, hipStream_t s)
{
    dim3 blk(256);
    if (N == 768) {
        constexpr int BM = 64, NWM = 1;
        int mtiles = 2048 / BM;
        int nwg = mtiles * (N / 128);
        dim3 grid(nwg);
        int nwg8 = nwg / 8;
        switch (epi) {
            case EPI_BF16:      gemm_p2_kernel<EPI_BF16, BM, NWM><<<grid, blk, 0, s>>>(A, B, bias, resid, out, N, K, mtiles, nwg8); break;
            case EPI_BF16_GELU: gemm_p2_kernel<EPI_BF16_GELU, BM, NWM><<<grid, blk, 0, s>>>(A, B, bias, resid, out, N, K, mtiles, nwg8); break;
            case EPI_F32_RESID: gemm_p2_kernel<EPI_F32_RESID, BM, NWM><<<grid, blk, 0, s>>>(A, B, bias, resid, out, N, K, mtiles, nwg8); break;
            default:            gemm_p2_kernel<EPI_F32, BM, NWM><<<grid, blk, 0, s>>>(A, B, bias, resid, out, N, K, mtiles, nwg8); break;
        }
    } else {
        constexpr int BM = 128, NWM = 2;
        int mtiles = 2048 / BM;
        int nwg = mtiles * (N / 128);
        dim3 grid(nwg);
        int nwg8 = nwg / 8;
        switch (epi) {
            case EPI_BF16:      gemm_p2_kernel<EPI_BF16, BM, NWM><<<grid, blk, 0, s>>>(A, B, bias, resid, out, N, K, mtiles, nwg8); break;
            case EPI_BF16_GELU: gemm_p2_kernel<EPI_BF16_GELU, BM, NWM><<<grid, blk, 0, s>>>(A, B, bias, resid, out, N, K, mtiles, nwg8); break;
            case EPI_F32_RESID: gemm_p2_kernel<EPI_F32_RESID, BM, NWM><<<grid, blk, 0, s>>>(A, B, bias, resid, out, N, K, mtiles, nwg8); break;
            default:            gemm_p2_kernel<EPI_F32, BM, NWM><<<grid, blk, 0, s>>>(A, B, bias, resid, out, N, K, mtiles, nwg8); break;
        }
    }
}

static void launch_gemm_f32w(int epi, const u16* A, const float* Bw, const float* bias,
                             const float* resid, void* out, int N, int K, hipStream_t s)
{
    dim3 grid((2048 / 128) * (N / 128)), blk(256);
    switch (epi) {
        case EPI_BF16:      gemm_kernel<EPI_BF16><<<grid, blk, 0, s>>>(A, Bw, bias, resid, out, N, K); break;
        case EPI_BF16_GELU: gemm_kernel<EPI_BF16_GELU><<<grid, blk, 0, s>>>(A, Bw, bias, resid, out, N, K); break;
        case EPI_F32_RESID: gemm_kernel<EPI_F32_RESID><<<grid, blk, 0, s>>>(A, Bw, bias, resid, out, N, K); break;
        default:            gemm_kernel<EPI_F32><<<grid, blk, 0, s>>>(A, Bw, bias, resid, out, N, K); break;
    }
}

static void cvt(const float* src, u16* dst, size_t n, hipStream_t s) {
    int n4 = (int)(n / 4);
    int blocks = (n4 + 255) / 256;
    if (blocks > 2048) blocks = 2048;
    cvt_kernel<<<blocks, 256, 0, s>>>(src, dst, n4);
}

extern "C" void kernel_launch(void* const* d_in, const int* in_sizes, int n_in,
                              void* d_out, int out_size, void* d_ws, size_t ws_size,
                              hipStream_t stream)
{
    (void)in_sizes; (void)n_in; (void)out_size;
    const int*   idx    = (const int*)  d_in[0];
    const float* age    = (const float*)d_in[1];
    const float* wte    = (const float*)d_in[2];
    const float* wae_w  = (const float*)d_in[3];
    const float* ln1_w  = (const float*)d_in[4];
    const float* ln1_b  = (const float*)d_in[5];
    const float* attn_w = (const float*)d_in[6];
    const float* attn_b = (const float*)d_in[7];
    const float* proj_w = (const float*)d_in[8];
    const float* proj_b = (const float*)d_in[9];
    const float* ln2_w  = (const float*)d_in[10];
    const float* ln2_b  = (const float*)d_in[11];
    const float* fc_w   = (const float*)d_in[12];
    const float* fc_b   = (const float*)d_in[13];
    const float* fc2_w  = (const float*)d_in[14];
    const float* fc2_b  = (const float*)d_in[15];
    const float* lnf_w  = (const float*)d_in[16];
    const float* lnf_b  = (const float*)d_in[17];

    char* ws = (char*)d_ws;
    size_t off = 0;
    float* x   = (float*)(ws + off); off += (size_t)2048 * 768 * 4;
    u16* hb    = (u16*)(ws + off);   off += (size_t)2048 * 768 * 2;
    u16* qkvb  = (u16*)(ws + off);   off += (size_t)2048 * 2304 * 2;
    u16* yvb   = (u16*)(ws + off);   off += (size_t)2048 * 768 * 2;
    u16* a1b   = (u16*)(ws + off);   off += (size_t)2048 * 3072 * 2;
    u16* yage  = (u16*)(ws + off);   off += (size_t)2048 * 768 * 2;
    // bf16 weight mirrors
    u16* wte_b  = (u16*)(ws + off);  off += (size_t)32768 * 768 * 2;
    u16* attn_wb= (u16*)(ws + off);  off += (size_t)4 * 2304 * 768 * 2;
    u16* proj_wb= (u16*)(ws + off);  off += (size_t)4 * 768 * 768 * 2;
    u16* fc_wb  = (u16*)(ws + off);  off += (size_t)4 * 3072 * 768 * 2;
    u16* fc2_wb = (u16*)(ws + off);  off += (size_t)4 * 768 * 3072 * 2;
    u16* wae_wb = (u16*)(ws + off);  off += (size_t)768 * 768 * 2;
    const size_t NEED = off;

    if (ws_size >= NEED) {
        cvt(wte,    wte_b,   (size_t)32768 * 768, stream);
        cvt(attn_w, attn_wb, (size_t)4 * 2304 * 768, stream);
        cvt(proj_w, proj_wb, (size_t)4 * 768 * 768, stream);
        cvt(fc_w,   fc_wb,   (size_t)4 * 3072 * 768, stream);
        cvt(fc2_w,  fc2_wb,  (size_t)4 * 768 * 3072, stream);
        cvt(wae_w,  wae_wb,  (size_t)768 * 768, stream);

        embed_kernel<<<2048, 256, 0, stream>>>(idx, age, wte, x, yage);
        launch_gemm_db(EPI_F32_RESID, yage, wae_wb, nullptr, x, x, 768, 768, stream);

        for (int li = 0; li < 4; li++) {
            ln_kernel<<<2048, 256, 0, stream>>>(x, ln1_w + li * 768, ln1_b + li * 768, hb);
            launch_gemm_db(EPI_BF16, hb, attn_wb + (size_t)li * 2304 * 768, attn_b + li * 2304,
                           nullptr, qkvb, 2304, 768, stream);
            attn_kernel<<<2 * 12 * 16, 256, 0, stream>>>(qkvb, idx, yvb);
            launch_gemm_db(EPI_F32_RESID, yvb, proj_wb + (size_t)li * 768 * 768, proj_b + li * 768,
                           x, x, 768, 768, stream);
            ln_kernel<<<2048, 256, 0, stream>>>(x, ln2_w + li * 768, ln2_b + li * 768, hb);
            launch_gemm_db(EPI_BF16_GELU, hb, fc_wb + (size_t)li * 3072 * 768, fc_b + li * 3072,
                           nullptr, a1b, 3072, 768, stream);
            launch_gemm_db(EPI_F32_RESID, a1b, fc2_wb + (size_t)li * 768 * 3072, fc2_b + li * 768,
                           x, x, 768, 3072, stream);
        }

        ln_kernel<<<2048, 256, 0, stream>>>(x, lnf_w, lnf_b, hb);
        launch_gemm_db(EPI_F32, hb, wte_b, nullptr, nullptr, d_out, 32768, 768, stream);
    } else {
        // fallback: fp32-weight path
        embed_kernel<<<2048, 256, 0, stream>>>(idx, age, wte, x, yage);
        launch_gemm_f32w(EPI_F32_RESID, yage, wae_w, nullptr, x, x, 768, 768, stream);
        for (int li = 0; li < 4; li++) {
            ln_kernel<<<2048, 256, 0, stream>>>(x, ln1_w + li * 768, ln1_b + li * 768, hb);
            launch_gemm_f32w(EPI_BF16, hb, attn_w + (size_t)li * 2304 * 768, attn_b + li * 2304,
                             nullptr, qkvb, 2304, 768, stream);
            attn_kernel<<<2 * 12 * 16, 256, 0, stream>>>(qkvb, idx, yvb);
            launch_gemm_f32w(EPI_F32_RESID, yvb, proj_w + (size_t)li * 768 * 768, proj_b + li * 768,
                             x, x, 768, 768, stream);
            ln_kernel<<<2048, 256, 0, stream>>>(x, ln2_w + li * 768, ln2_b + li * 768, hb);
            launch_gemm_f32w(EPI_BF16_GELU, hb, fc_w + (size_t)li * 3072 * 768, fc_b + li * 3072,
                             nullptr, a1b, 3072, 768, stream);
            launch_gemm_f32w(EPI_F32_RESID, a1b, fc2_w + (size_t)li * 768 * 3072, fc2_b + li * 768,
                             x, x, 768, 3072, stream);
        }
        ln_kernel<<<2048, 256, 0, stream>>>(x, lnf_w, lnf_b, hb);
        launch_gemm_f32w(EPI_F32, hb, wte, nullptr, nullptr, d_out, 32768, 768, stream);
    }
}